// Round 6
// baseline (673.998 us; speedup 1.0000x reference)
//
#include <hip/hip_runtime.h>
#include <math.h>

#define BETA_C   0.99f
#define TOL_C    1e-4f
#define MAXIT_C  1000
#define EPS_C    1e-3f
#define BN       65536
#define NN       32
#define HFD      25
#define HVD      128
#define KVD      8
#define G        16   // lanes per cooperative group (1 sample per group)
#define GPB      16   // groups per 256-thread block (k_setup)
#define SGPB     4    // groups per 64-thread block (k_solve)
#define NQBLK    2048 // persistent solver blocks (8 waves/CU, ~2 samples/group)

// wave-internal LDS ordering (groups live inside one wave; no block barrier
// inside the divergent solve loop).
__device__ __forceinline__ void wsync() {
    __builtin_amdgcn_wave_barrier();
    __threadfence_block();
    __builtin_amdgcn_wave_barrier();
}

__device__ __forceinline__ float sp_(float x) {
    return fmaxf(x, 0.f) + log1pf(expf(-fabsf(x)));
}
__device__ __forceinline__ void spsig_(float x, float& sp, float& sg) {
    float t = expf(-fabsf(x));
    sp = fmaxf(x, 0.f) + log1pf(t);
    float r = 1.f / (1.f + t);
    sg = (x >= 0.f) ? r : t * r;
}
__device__ __forceinline__ float sgn_(float d) {
    return (d > 0.f) ? 1.f : ((d < 0.f) ? -1.f : 0.f);
}

// ---------------------------------------------------------------------------
// layer1 (global W1 — 16 KB, L1-resident): u_k = fx . W1[:,k], lane's 8 k's
__device__ __forceinline__ void layer1_u2(
    const int gl, const float* __restrict__ fxa, const float* __restrict__ fxb,
    const float* __restrict__ vW1, float (&ua)[8], float (&ub)[8])
{
    const int k0 = gl * 8;
#pragma unroll
    for (int j = 0; j < 8; ++j) { ua[j] = 0.f; ub[j] = 0.f; }
#pragma unroll
    for (int i = 0; i < NN; ++i) {
        const float4 wa = *(const float4*)(vW1 + i * HVD + k0);
        const float4 wb = *(const float4*)(vW1 + i * HVD + k0 + 4);
        const float xa = fxa[i], xb = fxb[i];
        ua[0] = fmaf(xa, wa.x, ua[0]); ua[1] = fmaf(xa, wa.y, ua[1]);
        ua[2] = fmaf(xa, wa.z, ua[2]); ua[3] = fmaf(xa, wa.w, ua[3]);
        ua[4] = fmaf(xa, wb.x, ua[4]); ua[5] = fmaf(xa, wb.y, ua[5]);
        ua[6] = fmaf(xa, wb.z, ua[6]); ua[7] = fmaf(xa, wb.w, ua[7]);
        ub[0] = fmaf(xb, wa.x, ub[0]); ub[1] = fmaf(xb, wa.y, ub[1]);
        ub[2] = fmaf(xb, wa.z, ub[2]); ub[3] = fmaf(xb, wa.w, ub[3]);
        ub[4] = fmaf(xb, wb.x, ub[4]); ub[5] = fmaf(xb, wb.y, ub[5]);
        ub[6] = fmaf(xb, wb.z, ub[6]); ub[7] = fmaf(xb, wb.w, ub[7]);
    }
}

__device__ __forceinline__ void layer1_u1(
    const int gl, const float* __restrict__ fx,
    const float* __restrict__ vW1, float (&u)[8])
{
    const int k0 = gl * 8;
#pragma unroll
    for (int j = 0; j < 8; ++j) u[j] = 0.f;
#pragma unroll
    for (int i = 0; i < NN; ++i) {
        const float4 wa = *(const float4*)(vW1 + i * HVD + k0);
        const float4 wb = *(const float4*)(vW1 + i * HVD + k0 + 4);
        const float xv = fx[i];
        u[0] = fmaf(xv, wa.x, u[0]); u[1] = fmaf(xv, wa.y, u[1]);
        u[2] = fmaf(xv, wa.z, u[2]); u[3] = fmaf(xv, wa.w, u[3]);
        u[4] = fmaf(xv, wb.x, u[4]); u[5] = fmaf(xv, wb.y, u[5]);
        u[6] = fmaf(xv, wb.z, u[6]); u[7] = fmaf(xv, wb.w, u[7]);
    }
}

// ---------------------------------------------------------------------------
// batched B=2 plain eval at g=1 (k_setup): inputs via cached u; h1 rows float
__device__ __forceinline__ void veval2_plain(
    const int gl, const float (&ua)[8], const float (&ub)[8],
    float* __restrict__ h1a, float* __restrict__ h1b,
    const float n2a, const float n2b,
    const float* __restrict__ vb1, const float* __restrict__ vW2,
    const float* __restrict__ vb2, const float* __restrict__ vW3,
    const float* __restrict__ vb3, const float* __restrict__ h0g,
    float& Va, float& Vb)
{
    const int k0 = gl * 8;
    {
        const float4 b1a = *(const float4*)(vb1 + k0);
        const float4 b1b = *(const float4*)(vb1 + k0 + 4);
        const float bv[8] = {b1a.x, b1a.y, b1a.z, b1a.w, b1b.x, b1b.y, b1b.z, b1b.w};
        float4 va0, va1, vb0, vb1v;
        va0.x = sp_(ua[0] + bv[0]); va0.y = sp_(ua[1] + bv[1]);
        va0.z = sp_(ua[2] + bv[2]); va0.w = sp_(ua[3] + bv[3]);
        va1.x = sp_(ua[4] + bv[4]); va1.y = sp_(ua[5] + bv[5]);
        va1.z = sp_(ua[6] + bv[6]); va1.w = sp_(ua[7] + bv[7]);
        vb0.x = sp_(ub[0] + bv[0]); vb0.y = sp_(ub[1] + bv[1]);
        vb0.z = sp_(ub[2] + bv[2]); vb0.w = sp_(ub[3] + bv[3]);
        vb1v.x = sp_(ub[4] + bv[4]); vb1v.y = sp_(ub[5] + bv[5]);
        vb1v.z = sp_(ub[6] + bv[6]); vb1v.w = sp_(ub[7] + bv[7]);
        *(float4*)(h1a + k0) = va0; *(float4*)(h1a + k0 + 4) = va1;
        *(float4*)(h1b + k0) = vb0; *(float4*)(h1b + k0 + 4) = vb1v;
    }
    wsync();
    float aa[8], ab[8];
#pragma unroll
    for (int j = 0; j < 8; ++j) { aa[j] = 0.f; ab[j] = 0.f; }
#pragma unroll 4
    for (int k = 0; k < HVD; ++k) {
        const float ha = h1a[k], hb = h1b[k];           // LDS broadcast
        const float4 wa = *(const float4*)(vW2 + k * HVD + k0);
        const float4 wb = *(const float4*)(vW2 + k * HVD + k0 + 4);
        aa[0] = fmaf(ha, wa.x, aa[0]); aa[1] = fmaf(ha, wa.y, aa[1]);
        aa[2] = fmaf(ha, wa.z, aa[2]); aa[3] = fmaf(ha, wa.w, aa[3]);
        aa[4] = fmaf(ha, wb.x, aa[4]); aa[5] = fmaf(ha, wb.y, aa[5]);
        aa[6] = fmaf(ha, wb.z, aa[6]); aa[7] = fmaf(ha, wb.w, aa[7]);
        ab[0] = fmaf(hb, wa.x, ab[0]); ab[1] = fmaf(hb, wa.y, ab[1]);
        ab[2] = fmaf(hb, wa.z, ab[2]); ab[3] = fmaf(hb, wa.w, ab[3]);
        ab[4] = fmaf(hb, wb.x, ab[4]); ab[5] = fmaf(hb, wb.y, ab[5]);
        ab[6] = fmaf(hb, wb.z, ab[6]); ab[7] = fmaf(hb, wb.w, ab[7]);
    }
    wsync();
    float oa[KVD], ob[KVD];
#pragma unroll
    for (int c = 0; c < KVD; ++c) { oa[c] = 0.f; ob[c] = 0.f; }
    {
        const float4 b2a = *(const float4*)(vb2 + k0);
        const float4 b2b = *(const float4*)(vb2 + k0 + 4);
        const float bv[8] = {b2a.x, b2a.y, b2a.z, b2a.w, b2b.x, b2b.y, b2b.z, b2b.w};
#pragma unroll
        for (int j = 0; j < 8; ++j) {
            const float h2a = sp_(aa[j] + bv[j]);
            const float h2b = sp_(ab[j] + bv[j]);
            const float4 w3a = *(const float4*)(vW3 + (k0 + j) * KVD);
            const float4 w3b = *(const float4*)(vW3 + (k0 + j) * KVD + 4);
            oa[0] = fmaf(h2a, w3a.x, oa[0]); oa[1] = fmaf(h2a, w3a.y, oa[1]);
            oa[2] = fmaf(h2a, w3a.z, oa[2]); oa[3] = fmaf(h2a, w3a.w, oa[3]);
            oa[4] = fmaf(h2a, w3b.x, oa[4]); oa[5] = fmaf(h2a, w3b.y, oa[5]);
            oa[6] = fmaf(h2a, w3b.z, oa[6]); oa[7] = fmaf(h2a, w3b.w, oa[7]);
            ob[0] = fmaf(h2b, w3a.x, ob[0]); ob[1] = fmaf(h2b, w3a.y, ob[1]);
            ob[2] = fmaf(h2b, w3a.z, ob[2]); ob[3] = fmaf(h2b, w3a.w, ob[3]);
            ob[4] = fmaf(h2b, w3b.x, ob[4]); ob[5] = fmaf(h2b, w3b.y, ob[5]);
            ob[6] = fmaf(h2b, w3b.z, ob[6]); ob[7] = fmaf(h2b, w3b.w, ob[7]);
        }
    }
#pragma unroll
    for (int m = 1; m < G; m <<= 1) {
#pragma unroll
        for (int c = 0; c < KVD; ++c) {
            oa[c] += __shfl_xor(oa[c], m);
            ob[c] += __shfl_xor(ob[c], m);
        }
    }
    float vva = 0.f, vvb = 0.f;
#pragma unroll
    for (int c = 0; c < KVD; ++c) {
        const float da = (oa[c] + vb3[c]) - h0g[c];
        const float db = (ob[c] + vb3[c]) - h0g[c];
        vva = fmaf(da, da, vva);
        vvb = fmaf(db, db, vvb);
    }
    Va = vva + EPS_C * n2a;   // g = 1
    Vb = vvb + EPS_C * n2b;
}

// ---------------------------------------------------------------------------
// single TAN eval from cached u (k_solve): V(fx*g), dV/dg
__device__ __forceinline__ void veval1_tan(
    const int gl, const float (&u)[8], const float g,
    float2* h1row, const float n2,
    const float* __restrict__ vb1, const float* __restrict__ vW2,
    const float* __restrict__ vb2, const float* __restrict__ vW3,
    const float* __restrict__ vb3, const float* __restrict__ h0g,
    float& Vout, float& dVout)
{
    const int k0 = gl * 8;
    {
        const float4 b1a = *(const float4*)(vb1 + k0);
        const float4 b1b = *(const float4*)(vb1 + k0 + 4);
        const float bv[8] = {b1a.x, b1a.y, b1a.z, b1a.w, b1b.x, b1b.y, b1b.z, b1b.w};
#pragma unroll
        for (int j = 0; j < 8; ++j) {
            const float pre = fmaf(g, u[j], bv[j]);
            float sp, sg; spsig_(pre, sp, sg);
            h1row[k0 + j] = make_float2(sp, sg * u[j]);
        }
    }
    wsync();
    float acc[8], dacc[8];
#pragma unroll
    for (int j = 0; j < 8; ++j) { acc[j] = 0.f; dacc[j] = 0.f; }
#pragma unroll 4
    for (int k = 0; k < HVD; ++k) {
        const float2 hp = h1row[k];
        const float4 wa = *(const float4*)(vW2 + k * HVD + k0);
        const float4 wb = *(const float4*)(vW2 + k * HVD + k0 + 4);
        acc[0] = fmaf(hp.x, wa.x, acc[0]); acc[1] = fmaf(hp.x, wa.y, acc[1]);
        acc[2] = fmaf(hp.x, wa.z, acc[2]); acc[3] = fmaf(hp.x, wa.w, acc[3]);
        acc[4] = fmaf(hp.x, wb.x, acc[4]); acc[5] = fmaf(hp.x, wb.y, acc[5]);
        acc[6] = fmaf(hp.x, wb.z, acc[6]); acc[7] = fmaf(hp.x, wb.w, acc[7]);
        dacc[0] = fmaf(hp.y, wa.x, dacc[0]); dacc[1] = fmaf(hp.y, wa.y, dacc[1]);
        dacc[2] = fmaf(hp.y, wa.z, dacc[2]); dacc[3] = fmaf(hp.y, wa.w, dacc[3]);
        dacc[4] = fmaf(hp.y, wb.x, dacc[4]); dacc[5] = fmaf(hp.y, wb.y, dacc[5]);
        dacc[6] = fmaf(hp.y, wb.z, dacc[6]); dacc[7] = fmaf(hp.y, wb.w, dacc[7]);
    }
    wsync();
    float o[KVD], dO[KVD];
#pragma unroll
    for (int c = 0; c < KVD; ++c) { o[c] = 0.f; dO[c] = 0.f; }
    {
        const float4 b2a = *(const float4*)(vb2 + k0);
        const float4 b2b = *(const float4*)(vb2 + k0 + 4);
        const float bv[8] = {b2a.x, b2a.y, b2a.z, b2a.w, b2b.x, b2b.y, b2b.z, b2b.w};
#pragma unroll
        for (int j = 0; j < 8; ++j) {
            const float pre2 = acc[j] + bv[j];
            float h2, sg; spsig_(pre2, h2, sg);
            const float dh2 = sg * dacc[j];
            const float4 w3a = *(const float4*)(vW3 + (k0 + j) * KVD);
            const float4 w3b = *(const float4*)(vW3 + (k0 + j) * KVD + 4);
            o[0] = fmaf(h2, w3a.x, o[0]); o[1] = fmaf(h2, w3a.y, o[1]);
            o[2] = fmaf(h2, w3a.z, o[2]); o[3] = fmaf(h2, w3a.w, o[3]);
            o[4] = fmaf(h2, w3b.x, o[4]); o[5] = fmaf(h2, w3b.y, o[5]);
            o[6] = fmaf(h2, w3b.z, o[6]); o[7] = fmaf(h2, w3b.w, o[7]);
            dO[0] = fmaf(dh2, w3a.x, dO[0]); dO[1] = fmaf(dh2, w3a.y, dO[1]);
            dO[2] = fmaf(dh2, w3a.z, dO[2]); dO[3] = fmaf(dh2, w3a.w, dO[3]);
            dO[4] = fmaf(dh2, w3b.x, dO[4]); dO[5] = fmaf(dh2, w3b.y, dO[5]);
            dO[6] = fmaf(dh2, w3b.z, dO[6]); dO[7] = fmaf(dh2, w3b.w, dO[7]);
        }
    }
#pragma unroll
    for (int m = 1; m < G; m <<= 1) {
#pragma unroll
        for (int c = 0; c < KVD; ++c) {
            o[c] += __shfl_xor(o[c], m);
            dO[c] += __shfl_xor(dO[c], m);
        }
    }
    float vv = 0.f, dv = 0.f;
#pragma unroll
    for (int c = 0; c < KVD; ++c) {
        const float d = (o[c] + vb3[c]) - h0g[c];
        vv = fmaf(d, d, vv);
        dv = fmaf(d, dO[c], dv);
    }
    Vout = vv + EPS_C * g * g * n2;
    dVout = 2.f * dv + 2.f * EPS_C * g * n2;
}

// ---- h0 = V-MLP(0) : weight-only, one tiny block --------------------------
__global__ __launch_bounds__(128) void k_h0(
    const float* __restrict__ vb1, const float* __restrict__ vW2,
    const float* __restrict__ vb2, const float* __restrict__ vW3,
    const float* __restrict__ vb3, float* __restrict__ h0g)
{
    __shared__ float h1s[HVD];
    __shared__ float h2s[HVD];
    int j = threadIdx.x;
    h1s[j] = sp_(vb1[j]);
    __syncthreads();
    float a = vb2[j];
    for (int k = 0; k < HVD; ++k) a = fmaf(h1s[k], vW2[k * HVD + j], a);
    h2s[j] = sp_(a);
    __syncthreads();
    if (j < KVD) {
        float acc = vb3[j];
        for (int k = 0; k < HVD; ++k) acc = fmaf(h2s[k], vW3[k * KVD + j], acc);
        h0g[j] = acc;
    }
}

// ---- setup: R3 version — fhat, ONE batched global-weight pass -------------
__global__ __launch_bounds__(256, 3) void k_setup(
    const float* __restrict__ x_g,
    const float* __restrict__ fW1, const float* __restrict__ fb1,
    const float* __restrict__ fW2, const float* __restrict__ fb2,
    const float* __restrict__ fW3, const float* __restrict__ fb3,
    const float* __restrict__ vW1, const float* __restrict__ vb1,
    const float* __restrict__ vW2, const float* __restrict__ vb2,
    const float* __restrict__ vW3, const float* __restrict__ vb3,
    const float* __restrict__ h0g,
    float* __restrict__ out,
    int* __restrict__ cnt, int* __restrict__ list, float* __restrict__ tgt)
{
    __shared__ float h1s[GPB][2][HVD + 4];
    __shared__ float fxs[GPB][2][NN + 2];
    __shared__ float fh1[GPB][HFD + 1];
    __shared__ float fh2[GPB][HFD + 1];
    __shared__ int   wcnt[4];
    __shared__ int   bbase;

    const int gi = threadIdx.x >> 4;
    const int gl = threadIdx.x & (G - 1);
    const int s  = blockIdx.x * GPB + gi;
    float* xrow = fxs[gi][0];
    float* frow = fxs[gi][1];

    xrow[gl]      = x_g[(size_t)s * NN + gl];
    xrow[gl + 16] = x_g[(size_t)s * NN + gl + 16];
    wsync();

    // ---- fhat (lane-parallel over hidden units)
    for (int uu = gl; uu < HFD; uu += G) {
        float a = fb1[uu];
#pragma unroll
        for (int i = 0; i < NN; ++i) a = fmaf(xrow[i], fW1[i * HFD + uu], a);
        fh1[gi][uu] = sp_(a);
    }
    wsync();
    for (int uu = gl; uu < HFD; uu += G) {
        float a = fb2[uu];
#pragma unroll
        for (int i = 0; i < HFD; ++i) a = fmaf(fh1[gi][i], fW2[i * HFD + uu], a);
        fh2[gi][uu] = sp_(a);
    }
    wsync();
    float fo0 = fb3[gl], fo1 = fb3[gl + 16];
#pragma unroll
    for (int i = 0; i < HFD; ++i) {
        const float h = fh2[gi][i];
        fo0 = fmaf(h, fW3[i * NN + gl], fo0);
        fo1 = fmaf(h, fW3[i * NN + gl + 16], fo1);
    }
    frow[gl] = fo0; frow[gl + 16] = fo1;
    out[(size_t)s * NN + gl]      = fo0;
    out[(size_t)s * NN + gl + 16] = fo1;
    wsync();

    float n2x = 0.f, n2f = 0.f;
#pragma unroll
    for (int i = 0; i < NN; ++i) {
        n2x = fmaf(xrow[i], xrow[i], n2x);
        n2f = fmaf(frow[i], frow[i], n2f);
    }

    // ---- batched V eval over {x, fhatx}: one weight pass, 2x FMA density
    float ux[8], uf[8];
    layer1_u2(gl, xrow, frow, vW1, ux, uf);
    float Vx, Vf;
    veval2_plain(gl, ux, uf, h1s[gi][0], h1s[gi][1], n2x, n2f,
                 vb1, vW2, vb2, vW3, vb3, h0g, Vx, Vf);

    const float target = BETA_C * Vx;
    const bool active = (Vf - target) > 0.f;

    // compaction: one entry per active group, one atomicAdd per block
    const bool lead = active && (gl == 0);
    unsigned long long bal = __ballot(lead);
    const int lane = threadIdx.x & 63, wv = threadIdx.x >> 6;
    const int rank = __popcll(bal & ((1ull << lane) - 1ull));
    if (lane == 0) wcnt[wv] = __popcll(bal);
    __syncthreads();
    if (threadIdx.x == 0) {
        int tot = 0;
        for (int i = 0; i < 4; ++i) { int c = wcnt[i]; wcnt[i] = tot; tot += c; }
        bbase = atomicAdd(cnt, tot);
    }
    __syncthreads();
    if (lead) {
        const int p = bbase + wcnt[wv] + rank;
        list[p] = s;
        tgt[p] = target;
    }
}

// ---- solver: persistent groups + global work queue ------------------------
// Each 16-lane group grabs the next compacted sample when its own converges:
// wave time ~ sum of its samples' evals, not max-of-4; no block-slot tail.
// All control state (gamma, brackets, convergence) is group-uniform.
__global__ __launch_bounds__(64, 4) void k_solve(
    const float* __restrict__ vW1, const float* __restrict__ vb1,
    const float* __restrict__ vW2, const float* __restrict__ vb2,
    const float* __restrict__ vW3, const float* __restrict__ vb3,
    const float* __restrict__ h0g,
    float* __restrict__ out,
    const int* __restrict__ cnt, const int* __restrict__ list,
    const float* __restrict__ tgt, int* __restrict__ qhead)
{
    __shared__ float2 h1s[SGPB][HVD + 2];
    __shared__ float  fxs[SGPB][NN + 2];

    const int gi = threadIdx.x >> 4;
    const int gl = threadIdx.x & (G - 1);
    const int n  = *cnt;
    float2* h1row = h1s[gi];
    float*  fxrow = fxs[gi];
    const int lead = threadIdx.x & 48;      // wave lane of this group's lane 0

    int my;
    {
        int v = 0;
        if (gl == 0) v = atomicAdd(qhead, 1);
        my = __shfl(v, lead);
    }
    if (my >= n) return;                    // group-uniform

    int s; float target, f0, f1, n2;
    float u[8];
    float gamma, e1, e2, v_e1, v_e2;
    bool pend; int it;

    auto init_sample = [&]() {
        s = list[my]; target = tgt[my];
        f0 = out[(size_t)s * NN + gl];
        f1 = out[(size_t)s * NN + gl + 16];
        fxrow[gl] = f0; fxrow[gl + 16] = f1;
        wsync();
        n2 = 0.f;
#pragma unroll
        for (int i = 0; i < NN; ++i) n2 = fmaf(fxrow[i], fxrow[i], n2);
        layer1_u1(gl, fxrow, vW1, u);
        gamma = 1.f; e1 = 0.f; e2 = 1.f;
        v_e1 = 0.f;      // V(fx*0) == 0
        v_e2 = 0.f;      // set at it==0
        pend = false; it = 0;
    };
    init_sample();

    for (;;) {
        float vp, dv;
        veval1_tan(gl, u, gamma, h1row, n2,
                   vb1, vW2, vb2, vW3, vb3, h0g, vp, dv);
        if (pend) {
            const float sa = sgn_(vp - target);
            const float s1 = sgn_(v_e1 - target);
            const float s2 = sgn_(v_e2 - target);
            if (sa * s1 < 0.f) { e2 = gamma; v_e2 = vp; }
            if (sa * s2 < 0.f) { e1 = gamma; v_e1 = vp; }
            pend = false;
        }
        bool finish = false;
        if (it == 0) {
            v_e2 = vp;
        } else if (fabsf(vp - target) <= TOL_C) {
            finish = true;
        }
        if (!finish) {
            const float newt = gamma - (vp - target) / dv;
            if (newt >= e1 && newt <= e2) {   // NaN fails -> bisect
                gamma = newt;
            } else {
                gamma = 0.5f * (e1 + e2);
                pend = true;
            }
            ++it;
            if (it >= MAXIT_C) finish = true;
        }
        if (finish) {
            out[(size_t)s * NN + gl]      = f0 * gamma;
            out[(size_t)s * NN + gl + 16] = f1 * gamma;
            int v = 0;
            if (gl == 0) v = atomicAdd(qhead, 1);
            my = __shfl(v, lead);
            if (my >= n) break;               // group-uniform exit
            init_sample();
        }
    }
}

extern "C" void kernel_launch(void* const* d_in, const int* in_sizes, int n_in,
                              void* d_out, int out_size, void* d_ws, size_t ws_size,
                              hipStream_t stream)
{
    const float* x   = (const float*)d_in[0];
    const float* fW1 = (const float*)d_in[1];
    const float* fb1 = (const float*)d_in[2];
    const float* fW2 = (const float*)d_in[3];
    const float* fb2 = (const float*)d_in[4];
    const float* fW3 = (const float*)d_in[5];
    const float* fb3 = (const float*)d_in[6];
    const float* vW1 = (const float*)d_in[7];
    const float* vb1 = (const float*)d_in[8];
    const float* vW2 = (const float*)d_in[9];
    const float* vb2 = (const float*)d_in[10];
    const float* vW3 = (const float*)d_in[11];
    const float* vb3 = (const float*)d_in[12];
    float* out = (float*)d_out;

    char* ws = (char*)d_ws;
    int*   cnt   = (int*)ws;                                 // 4 B
    int*   qhead = (int*)(ws + 4);                           // 4 B
    float* h0g   = (float*)(ws + 64);                        // 8 floats
    int*   list  = (int*)(ws + 128);                         // BN ints
    float* tgt   = (float*)(ws + 128 + (size_t)BN * 4);      // BN floats

    hipMemsetAsync(ws, 0, 8, stream);                        // cnt + qhead

    hipLaunchKernelGGL(k_h0, dim3(1), dim3(HVD), 0, stream,
                       vb1, vW2, vb2, vW3, vb3, h0g);

    hipLaunchKernelGGL(k_setup, dim3(BN / GPB), dim3(256), 0, stream,
                       x, fW1, fb1, fW2, fb2, fW3, fb3,
                       vW1, vb1, vW2, vb2, vW3, vb3,
                       h0g, out, cnt, list, tgt);

    hipLaunchKernelGGL(k_solve, dim3(NQBLK), dim3(64), 0, stream,
                       vW1, vb1, vW2, vb2, vW3, vb3,
                       h0g, out, cnt, list, tgt, qhead);
}

// Round 7
// 576.330 us; speedup vs baseline: 1.1695x; 1.1695x over previous
//
#include <hip/hip_runtime.h>
#include <math.h>

#define BETA_C   0.99f
#define TOL_C    1e-4f
#define MAXIT_C  1000
#define EPS_C    1e-3f
#define BN       65536
#define NN       32
#define HFD      25
#define HVD      128
#define KVD      8
#define G        16   // lanes per cooperative group (1 sample per group)
#define GPB      16   // groups per 256-thread block (k_setup)
#define SGPB     4    // groups per 64-thread block (k_solve)
#define NQBLK    3072 // persistent solver blocks (queue-drained)

// wave-internal LDS ordering (groups live inside one wave; no block barrier
// inside the divergent solve loop).
__device__ __forceinline__ void wsync() {
    __builtin_amdgcn_wave_barrier();
    __threadfence_block();
    __builtin_amdgcn_wave_barrier();
}

__device__ __forceinline__ float sp_(float x) {
    return fmaxf(x, 0.f) + log1pf(expf(-fabsf(x)));
}
__device__ __forceinline__ void spsig_(float x, float& sp, float& sg) {
    float t = expf(-fabsf(x));
    sp = fmaxf(x, 0.f) + log1pf(t);
    float r = 1.f / (1.f + t);
    sg = (x >= 0.f) ? r : t * r;
}
__device__ __forceinline__ float sgn_(float d) {
    return (d > 0.f) ? 1.f : ((d < 0.f) ? -1.f : 0.f);
}

// ---------------------------------------------------------------------------
// layer1 (global W1 — 16 KB, L1-resident): u_k = fx . W1[:,k], lane's 8 k's
__device__ __forceinline__ void layer1_u2(
    const int gl, const float* __restrict__ fxa, const float* __restrict__ fxb,
    const float* __restrict__ vW1, float (&ua)[8], float (&ub)[8])
{
    const int k0 = gl * 8;
#pragma unroll
    for (int j = 0; j < 8; ++j) { ua[j] = 0.f; ub[j] = 0.f; }
#pragma unroll
    for (int i = 0; i < NN; ++i) {
        const float4 wa = *(const float4*)(vW1 + i * HVD + k0);
        const float4 wb = *(const float4*)(vW1 + i * HVD + k0 + 4);
        const float xa = fxa[i], xb = fxb[i];
        ua[0] = fmaf(xa, wa.x, ua[0]); ua[1] = fmaf(xa, wa.y, ua[1]);
        ua[2] = fmaf(xa, wa.z, ua[2]); ua[3] = fmaf(xa, wa.w, ua[3]);
        ua[4] = fmaf(xa, wb.x, ua[4]); ua[5] = fmaf(xa, wb.y, ua[5]);
        ua[6] = fmaf(xa, wb.z, ua[6]); ua[7] = fmaf(xa, wb.w, ua[7]);
        ub[0] = fmaf(xb, wa.x, ub[0]); ub[1] = fmaf(xb, wa.y, ub[1]);
        ub[2] = fmaf(xb, wa.z, ub[2]); ub[3] = fmaf(xb, wa.w, ub[3]);
        ub[4] = fmaf(xb, wb.x, ub[4]); ub[5] = fmaf(xb, wb.y, ub[5]);
        ub[6] = fmaf(xb, wb.z, ub[6]); ub[7] = fmaf(xb, wb.w, ub[7]);
    }
}

__device__ __forceinline__ void layer1_u1(
    const int gl, const float* __restrict__ fx,
    const float* __restrict__ vW1, float (&u)[8])
{
    const int k0 = gl * 8;
#pragma unroll
    for (int j = 0; j < 8; ++j) u[j] = 0.f;
#pragma unroll
    for (int i = 0; i < NN; ++i) {
        const float4 wa = *(const float4*)(vW1 + i * HVD + k0);
        const float4 wb = *(const float4*)(vW1 + i * HVD + k0 + 4);
        const float xv = fx[i];
        u[0] = fmaf(xv, wa.x, u[0]); u[1] = fmaf(xv, wa.y, u[1]);
        u[2] = fmaf(xv, wa.z, u[2]); u[3] = fmaf(xv, wa.w, u[3]);
        u[4] = fmaf(xv, wb.x, u[4]); u[5] = fmaf(xv, wb.y, u[5]);
        u[6] = fmaf(xv, wb.z, u[6]); u[7] = fmaf(xv, wb.w, u[7]);
    }
}

// ---------------------------------------------------------------------------
// batched B=2 plain eval at g=1 (k_setup): inputs via cached u; h1 rows float
__device__ __forceinline__ void veval2_plain(
    const int gl, const float (&ua)[8], const float (&ub)[8],
    float* __restrict__ h1a, float* __restrict__ h1b,
    const float n2a, const float n2b,
    const float* __restrict__ vb1, const float* __restrict__ vW2,
    const float* __restrict__ vb2, const float* __restrict__ vW3,
    const float* __restrict__ vb3, const float* __restrict__ h0g,
    float& Va, float& Vb)
{
    const int k0 = gl * 8;
    {
        const float4 b1a = *(const float4*)(vb1 + k0);
        const float4 b1b = *(const float4*)(vb1 + k0 + 4);
        const float bv[8] = {b1a.x, b1a.y, b1a.z, b1a.w, b1b.x, b1b.y, b1b.z, b1b.w};
        float4 va0, va1, vb0, vb1v;
        va0.x = sp_(ua[0] + bv[0]); va0.y = sp_(ua[1] + bv[1]);
        va0.z = sp_(ua[2] + bv[2]); va0.w = sp_(ua[3] + bv[3]);
        va1.x = sp_(ua[4] + bv[4]); va1.y = sp_(ua[5] + bv[5]);
        va1.z = sp_(ua[6] + bv[6]); va1.w = sp_(ua[7] + bv[7]);
        vb0.x = sp_(ub[0] + bv[0]); vb0.y = sp_(ub[1] + bv[1]);
        vb0.z = sp_(ub[2] + bv[2]); vb0.w = sp_(ub[3] + bv[3]);
        vb1v.x = sp_(ub[4] + bv[4]); vb1v.y = sp_(ub[5] + bv[5]);
        vb1v.z = sp_(ub[6] + bv[6]); vb1v.w = sp_(ub[7] + bv[7]);
        *(float4*)(h1a + k0) = va0; *(float4*)(h1a + k0 + 4) = va1;
        *(float4*)(h1b + k0) = vb0; *(float4*)(h1b + k0 + 4) = vb1v;
    }
    wsync();
    float aa[8], ab[8];
#pragma unroll
    for (int j = 0; j < 8; ++j) { aa[j] = 0.f; ab[j] = 0.f; }
#pragma unroll 4
    for (int k = 0; k < HVD; ++k) {
        const float ha = h1a[k], hb = h1b[k];           // LDS broadcast
        const float4 wa = *(const float4*)(vW2 + k * HVD + k0);
        const float4 wb = *(const float4*)(vW2 + k * HVD + k0 + 4);
        aa[0] = fmaf(ha, wa.x, aa[0]); aa[1] = fmaf(ha, wa.y, aa[1]);
        aa[2] = fmaf(ha, wa.z, aa[2]); aa[3] = fmaf(ha, wa.w, aa[3]);
        aa[4] = fmaf(ha, wb.x, aa[4]); aa[5] = fmaf(ha, wb.y, aa[5]);
        aa[6] = fmaf(ha, wb.z, aa[6]); aa[7] = fmaf(ha, wb.w, aa[7]);
        ab[0] = fmaf(hb, wa.x, ab[0]); ab[1] = fmaf(hb, wa.y, ab[1]);
        ab[2] = fmaf(hb, wa.z, ab[2]); ab[3] = fmaf(hb, wa.w, ab[3]);
        ab[4] = fmaf(hb, wb.x, ab[4]); ab[5] = fmaf(hb, wb.y, ab[5]);
        ab[6] = fmaf(hb, wb.z, ab[6]); ab[7] = fmaf(hb, wb.w, ab[7]);
    }
    wsync();
    float oa[KVD], ob[KVD];
#pragma unroll
    for (int c = 0; c < KVD; ++c) { oa[c] = 0.f; ob[c] = 0.f; }
    {
        const float4 b2a = *(const float4*)(vb2 + k0);
        const float4 b2b = *(const float4*)(vb2 + k0 + 4);
        const float bv[8] = {b2a.x, b2a.y, b2a.z, b2a.w, b2b.x, b2b.y, b2b.z, b2b.w};
#pragma unroll
        for (int j = 0; j < 8; ++j) {
            const float h2a = sp_(aa[j] + bv[j]);
            const float h2b = sp_(ab[j] + bv[j]);
            const float4 w3a = *(const float4*)(vW3 + (k0 + j) * KVD);
            const float4 w3b = *(const float4*)(vW3 + (k0 + j) * KVD + 4);
            oa[0] = fmaf(h2a, w3a.x, oa[0]); oa[1] = fmaf(h2a, w3a.y, oa[1]);
            oa[2] = fmaf(h2a, w3a.z, oa[2]); oa[3] = fmaf(h2a, w3a.w, oa[3]);
            oa[4] = fmaf(h2a, w3b.x, oa[4]); oa[5] = fmaf(h2a, w3b.y, oa[5]);
            oa[6] = fmaf(h2a, w3b.z, oa[6]); oa[7] = fmaf(h2a, w3b.w, oa[7]);
            ob[0] = fmaf(h2b, w3a.x, ob[0]); ob[1] = fmaf(h2b, w3a.y, ob[1]);
            ob[2] = fmaf(h2b, w3a.z, ob[2]); ob[3] = fmaf(h2b, w3a.w, ob[3]);
            ob[4] = fmaf(h2b, w3b.x, ob[4]); ob[5] = fmaf(h2b, w3b.y, ob[5]);
            ob[6] = fmaf(h2b, w3b.z, ob[6]); ob[7] = fmaf(h2b, w3b.w, ob[7]);
        }
    }
#pragma unroll
    for (int m = 1; m < G; m <<= 1) {
#pragma unroll
        for (int c = 0; c < KVD; ++c) {
            oa[c] += __shfl_xor(oa[c], m);
            ob[c] += __shfl_xor(ob[c], m);
        }
    }
    float vva = 0.f, vvb = 0.f;
#pragma unroll
    for (int c = 0; c < KVD; ++c) {
        const float da = (oa[c] + vb3[c]) - h0g[c];
        const float db = (ob[c] + vb3[c]) - h0g[c];
        vva = fmaf(da, da, vva);
        vvb = fmaf(db, db, vvb);
    }
    Va = vva + EPS_C * n2a;   // g = 1
    Vb = vvb + EPS_C * n2b;
}

// ---------------------------------------------------------------------------
// single TAN eval from cached u (k_solve): V(fx*g), dV/dg.
// Biases/offsets preloaded in regs; h1/dh1 packed as float4 pairs (2 k's).
__device__ __forceinline__ void veval1_tan(
    const int gl, const float (&u)[8], const float g,
    float4* h1q, const float n2,
    const float (&b1v)[8], const float (&b2v)[8], const float (&d0c)[8],
    const float* __restrict__ vW2, const float* __restrict__ vW3,
    float& Vout, float& dVout)
{
    const int k0 = gl * 8;
#pragma unroll
    for (int j = 0; j < 8; j += 2) {
        const float pre0 = fmaf(g, u[j],     b1v[j]);
        const float pre1 = fmaf(g, u[j + 1], b1v[j + 1]);
        float sp0, sg0, sp1, sg1;
        spsig_(pre0, sp0, sg0);
        spsig_(pre1, sp1, sg1);
        h1q[(k0 + j) >> 1] = make_float4(sp0, sg0 * u[j], sp1, sg1 * u[j + 1]);
    }
    wsync();
    float acc[8], dacc[8];
#pragma unroll
    for (int j = 0; j < 8; ++j) { acc[j] = 0.f; dacc[j] = 0.f; }
#pragma unroll 2
    for (int kk = 0; kk < HVD / 2; ++kk) {
        const float4 q = h1q[kk];                       // (h1,dh1) x 2 k's
        const float* w0 = vW2 + (2 * kk) * HVD + k0;
        const float4 wa0 = *(const float4*)(w0);
        const float4 wb0 = *(const float4*)(w0 + 4);
        const float4 wa1 = *(const float4*)(w0 + HVD);
        const float4 wb1 = *(const float4*)(w0 + HVD + 4);
        acc[0] = fmaf(q.x, wa0.x, acc[0]); acc[1] = fmaf(q.x, wa0.y, acc[1]);
        acc[2] = fmaf(q.x, wa0.z, acc[2]); acc[3] = fmaf(q.x, wa0.w, acc[3]);
        acc[4] = fmaf(q.x, wb0.x, acc[4]); acc[5] = fmaf(q.x, wb0.y, acc[5]);
        acc[6] = fmaf(q.x, wb0.z, acc[6]); acc[7] = fmaf(q.x, wb0.w, acc[7]);
        dacc[0] = fmaf(q.y, wa0.x, dacc[0]); dacc[1] = fmaf(q.y, wa0.y, dacc[1]);
        dacc[2] = fmaf(q.y, wa0.z, dacc[2]); dacc[3] = fmaf(q.y, wa0.w, dacc[3]);
        dacc[4] = fmaf(q.y, wb0.x, dacc[4]); dacc[5] = fmaf(q.y, wb0.y, dacc[5]);
        dacc[6] = fmaf(q.y, wb0.z, dacc[6]); dacc[7] = fmaf(q.y, wb0.w, dacc[7]);
        acc[0] = fmaf(q.z, wa1.x, acc[0]); acc[1] = fmaf(q.z, wa1.y, acc[1]);
        acc[2] = fmaf(q.z, wa1.z, acc[2]); acc[3] = fmaf(q.z, wa1.w, acc[3]);
        acc[4] = fmaf(q.z, wb1.x, acc[4]); acc[5] = fmaf(q.z, wb1.y, acc[5]);
        acc[6] = fmaf(q.z, wb1.z, acc[6]); acc[7] = fmaf(q.z, wb1.w, acc[7]);
        dacc[0] = fmaf(q.w, wa1.x, dacc[0]); dacc[1] = fmaf(q.w, wa1.y, dacc[1]);
        dacc[2] = fmaf(q.w, wa1.z, dacc[2]); dacc[3] = fmaf(q.w, wa1.w, dacc[3]);
        dacc[4] = fmaf(q.w, wb1.x, dacc[4]); dacc[5] = fmaf(q.w, wb1.y, dacc[5]);
        dacc[6] = fmaf(q.w, wb1.z, dacc[6]); dacc[7] = fmaf(q.w, wb1.w, dacc[7]);
    }
    wsync();
    float o[KVD], dO[KVD];
#pragma unroll
    for (int c = 0; c < KVD; ++c) { o[c] = 0.f; dO[c] = 0.f; }
#pragma unroll
    for (int j = 0; j < 8; ++j) {
        const float pre2 = acc[j] + b2v[j];
        float h2, sg; spsig_(pre2, h2, sg);
        const float dh2 = sg * dacc[j];
        const float4 w3a = *(const float4*)(vW3 + (k0 + j) * KVD);
        const float4 w3b = *(const float4*)(vW3 + (k0 + j) * KVD + 4);
        o[0] = fmaf(h2, w3a.x, o[0]); o[1] = fmaf(h2, w3a.y, o[1]);
        o[2] = fmaf(h2, w3a.z, o[2]); o[3] = fmaf(h2, w3a.w, o[3]);
        o[4] = fmaf(h2, w3b.x, o[4]); o[5] = fmaf(h2, w3b.y, o[5]);
        o[6] = fmaf(h2, w3b.z, o[6]); o[7] = fmaf(h2, w3b.w, o[7]);
        dO[0] = fmaf(dh2, w3a.x, dO[0]); dO[1] = fmaf(dh2, w3a.y, dO[1]);
        dO[2] = fmaf(dh2, w3a.z, dO[2]); dO[3] = fmaf(dh2, w3a.w, dO[3]);
        dO[4] = fmaf(dh2, w3b.x, dO[4]); dO[5] = fmaf(dh2, w3b.y, dO[5]);
        dO[6] = fmaf(dh2, w3b.z, dO[6]); dO[7] = fmaf(dh2, w3b.w, dO[7]);
    }
#pragma unroll
    for (int m = 1; m < G; m <<= 1) {
#pragma unroll
        for (int c = 0; c < KVD; ++c) {
            o[c] += __shfl_xor(o[c], m);
            dO[c] += __shfl_xor(dO[c], m);
        }
    }
    float vv = 0.f, dv = 0.f;
#pragma unroll
    for (int c = 0; c < KVD; ++c) {
        const float d = o[c] + d0c[c];
        vv = fmaf(d, d, vv);
        dv = fmaf(d, dO[c], dv);
    }
    Vout = vv + EPS_C * g * g * n2;
    dVout = 2.f * dv + 2.f * EPS_C * g * n2;
}

// ---- h0 = V-MLP(0) : weight-only, one tiny block --------------------------
__global__ __launch_bounds__(128) void k_h0(
    const float* __restrict__ vb1, const float* __restrict__ vW2,
    const float* __restrict__ vb2, const float* __restrict__ vW3,
    const float* __restrict__ vb3, float* __restrict__ h0g)
{
    __shared__ float h1s[HVD];
    __shared__ float h2s[HVD];
    int j = threadIdx.x;
    h1s[j] = sp_(vb1[j]);
    __syncthreads();
    float a = vb2[j];
    for (int k = 0; k < HVD; ++k) a = fmaf(h1s[k], vW2[k * HVD + j], a);
    h2s[j] = sp_(a);
    __syncthreads();
    if (j < KVD) {
        float acc = vb3[j];
        for (int k = 0; k < HVD; ++k) acc = fmaf(h2s[k], vW3[k * KVD + j], acc);
        h0g[j] = acc;
    }
}

// ---- setup: fhat, ONE batched global-weight pass (R3 version, known-good) --
__global__ __launch_bounds__(256, 3) void k_setup(
    const float* __restrict__ x_g,
    const float* __restrict__ fW1, const float* __restrict__ fb1,
    const float* __restrict__ fW2, const float* __restrict__ fb2,
    const float* __restrict__ fW3, const float* __restrict__ fb3,
    const float* __restrict__ vW1, const float* __restrict__ vb1,
    const float* __restrict__ vW2, const float* __restrict__ vb2,
    const float* __restrict__ vW3, const float* __restrict__ vb3,
    const float* __restrict__ h0g,
    float* __restrict__ out,
    int* __restrict__ cnt, int* __restrict__ list, float* __restrict__ tgt)
{
    __shared__ float h1s[GPB][2][HVD + 4];
    __shared__ float fxs[GPB][2][NN + 2];
    __shared__ float fh1[GPB][HFD + 1];
    __shared__ float fh2[GPB][HFD + 1];
    __shared__ int   wcnt[4];
    __shared__ int   bbase;

    const int gi = threadIdx.x >> 4;
    const int gl = threadIdx.x & (G - 1);
    const int s  = blockIdx.x * GPB + gi;
    float* xrow = fxs[gi][0];
    float* frow = fxs[gi][1];

    xrow[gl]      = x_g[(size_t)s * NN + gl];
    xrow[gl + 16] = x_g[(size_t)s * NN + gl + 16];
    wsync();

    // ---- fhat (lane-parallel over hidden units)
    for (int uu = gl; uu < HFD; uu += G) {
        float a = fb1[uu];
#pragma unroll
        for (int i = 0; i < NN; ++i) a = fmaf(xrow[i], fW1[i * HFD + uu], a);
        fh1[gi][uu] = sp_(a);
    }
    wsync();
    for (int uu = gl; uu < HFD; uu += G) {
        float a = fb2[uu];
#pragma unroll
        for (int i = 0; i < HFD; ++i) a = fmaf(fh1[gi][i], fW2[i * HFD + uu], a);
        fh2[gi][uu] = sp_(a);
    }
    wsync();
    float fo0 = fb3[gl], fo1 = fb3[gl + 16];
#pragma unroll
    for (int i = 0; i < HFD; ++i) {
        const float h = fh2[gi][i];
        fo0 = fmaf(h, fW3[i * NN + gl], fo0);
        fo1 = fmaf(h, fW3[i * NN + gl + 16], fo1);
    }
    frow[gl] = fo0; frow[gl + 16] = fo1;
    out[(size_t)s * NN + gl]      = fo0;
    out[(size_t)s * NN + gl + 16] = fo1;
    wsync();

    float n2x = 0.f, n2f = 0.f;
#pragma unroll
    for (int i = 0; i < NN; ++i) {
        n2x = fmaf(xrow[i], xrow[i], n2x);
        n2f = fmaf(frow[i], frow[i], n2f);
    }

    // ---- batched V eval over {x, fhatx}: one weight pass, 2x FMA density
    float ux[8], uf[8];
    layer1_u2(gl, xrow, frow, vW1, ux, uf);
    float Vx, Vf;
    veval2_plain(gl, ux, uf, h1s[gi][0], h1s[gi][1], n2x, n2f,
                 vb1, vW2, vb2, vW3, vb3, h0g, Vx, Vf);

    const float target = BETA_C * Vx;
    const bool active = (Vf - target) > 0.f;

    // compaction: one entry per active group, one atomicAdd per block
    const bool lead = active && (gl == 0);
    unsigned long long bal = __ballot(lead);
    const int lane = threadIdx.x & 63, wv = threadIdx.x >> 6;
    const int rank = __popcll(bal & ((1ull << lane) - 1ull));
    if (lane == 0) wcnt[wv] = __popcll(bal);
    __syncthreads();
    if (threadIdx.x == 0) {
        int tot = 0;
        for (int i = 0; i < 4; ++i) { int c = wcnt[i]; wcnt[i] = tot; tot += c; }
        bbase = atomicAdd(cnt, tot);
    }
    __syncthreads();
    if (lead) {
        const int p = bbase + wcnt[wv] + rank;
        list[p] = s;
        tgt[p] = target;
    }
}

// ---- solver: persistent groups + global work queue ------------------------
// launch_bounds(64,2): VGPR cap 256 — R5's (64,4) yielded a 64-VGPR alloc and
// ~100 MB of scratch spill traffic (FETCH 39 MB / WRITE 60 MB).
__global__ __launch_bounds__(64, 2) void k_solve(
    const float* __restrict__ vW1, const float* __restrict__ vb1,
    const float* __restrict__ vW2, const float* __restrict__ vb2,
    const float* __restrict__ vW3, const float* __restrict__ vb3,
    const float* __restrict__ h0g,
    float* __restrict__ out,
    const int* __restrict__ cnt, const int* __restrict__ list,
    const float* __restrict__ tgt, int* __restrict__ qhead)
{
    __shared__ __align__(16) float4 h1s[SGPB][HVD / 2 + 1];
    __shared__ float fxs[SGPB][NN + 2];

    const int gi = threadIdx.x >> 4;
    const int gl = threadIdx.x & (G - 1);
    const int n  = *cnt;
    float4* h1q  = h1s[gi];
    float*  fxrow = fxs[gi];
    const int lead = threadIdx.x & 48;      // wave lane of this group's lane 0

    int my;
    {
        int v = 0;
        if (gl == 0) v = atomicAdd(qhead, 1);
        my = __shfl(v, lead);
    }
    if (my >= n) return;                    // group-uniform

    // per-kernel invariants in registers
    const int k0 = gl * 8;
    float b1v[8], b2v[8], d0c[8];
    {
        const float4 a = *(const float4*)(vb1 + k0);
        const float4 b = *(const float4*)(vb1 + k0 + 4);
        b1v[0]=a.x; b1v[1]=a.y; b1v[2]=a.z; b1v[3]=a.w;
        b1v[4]=b.x; b1v[5]=b.y; b1v[6]=b.z; b1v[7]=b.w;
        const float4 c = *(const float4*)(vb2 + k0);
        const float4 d = *(const float4*)(vb2 + k0 + 4);
        b2v[0]=c.x; b2v[1]=c.y; b2v[2]=c.z; b2v[3]=c.w;
        b2v[4]=d.x; b2v[5]=d.y; b2v[6]=d.z; b2v[7]=d.w;
#pragma unroll
        for (int cix = 0; cix < KVD; ++cix) d0c[cix] = vb3[cix] - h0g[cix];
    }

    int s; float target, f0, f1, n2;
    float u[8];
    float gamma, e1, e2, v_e1, v_e2;
    bool pend; int it;

    auto init_sample = [&]() {
        s = list[my]; target = tgt[my];
        f0 = out[(size_t)s * NN + gl];
        f1 = out[(size_t)s * NN + gl + 16];
        fxrow[gl] = f0; fxrow[gl + 16] = f1;
        wsync();
        n2 = 0.f;
#pragma unroll
        for (int i = 0; i < NN; ++i) n2 = fmaf(fxrow[i], fxrow[i], n2);
        layer1_u1(gl, fxrow, vW1, u);
        gamma = 1.f; e1 = 0.f; e2 = 1.f;
        v_e1 = 0.f;      // V(fx*0) == 0 (target > 0, so sign(-target) < 0)
        v_e2 = 0.f;      // set at it==0
        pend = false; it = 0;
    };
    init_sample();

    for (;;) {
        float vp, dv;
        veval1_tan(gl, u, gamma, h1q, n2, b1v, b2v, d0c, vW2, vW3, vp, dv);
        if (pend) {
            const float sa = sgn_(vp - target);
            const float s1 = sgn_(v_e1 - target);
            const float s2 = sgn_(v_e2 - target);
            if (sa * s1 < 0.f) { e2 = gamma; v_e2 = vp; }
            if (sa * s2 < 0.f) { e1 = gamma; v_e1 = vp; }
            pend = false;
        }
        bool finish = false;
        if (it == 0) {
            v_e2 = vp;
        } else if (fabsf(vp - target) <= TOL_C) {
            finish = true;
        }
        if (!finish) {
            const float newt = gamma - (vp - target) / dv;
            if (newt >= e1 && newt <= e2) {   // NaN fails -> bisect
                gamma = newt;
            } else {
                gamma = 0.5f * (e1 + e2);
                pend = true;
            }
            ++it;
            if (it >= MAXIT_C) finish = true;
        }
        if (finish) {
            out[(size_t)s * NN + gl]      = f0 * gamma;
            out[(size_t)s * NN + gl + 16] = f1 * gamma;
            int v = 0;
            if (gl == 0) v = atomicAdd(qhead, 1);
            my = __shfl(v, lead);
            if (my >= n) break;               // group-uniform exit
            init_sample();
        }
    }
}

extern "C" void kernel_launch(void* const* d_in, const int* in_sizes, int n_in,
                              void* d_out, int out_size, void* d_ws, size_t ws_size,
                              hipStream_t stream)
{
    const float* x   = (const float*)d_in[0];
    const float* fW1 = (const float*)d_in[1];
    const float* fb1 = (const float*)d_in[2];
    const float* fW2 = (const float*)d_in[3];
    const float* fb2 = (const float*)d_in[4];
    const float* fW3 = (const float*)d_in[5];
    const float* fb3 = (const float*)d_in[6];
    const float* vW1 = (const float*)d_in[7];
    const float* vb1 = (const float*)d_in[8];
    const float* vW2 = (const float*)d_in[9];
    const float* vb2 = (const float*)d_in[10];
    const float* vW3 = (const float*)d_in[11];
    const float* vb3 = (const float*)d_in[12];
    float* out = (float*)d_out;

    char* ws = (char*)d_ws;
    int*   cnt   = (int*)ws;                                 // 4 B
    int*   qhead = (int*)(ws + 4);                           // 4 B
    float* h0g   = (float*)(ws + 64);                        // 8 floats
    int*   list  = (int*)(ws + 128);                         // BN ints
    float* tgt   = (float*)(ws + 128 + (size_t)BN * 4);      // BN floats

    hipMemsetAsync(ws, 0, 8, stream);                        // cnt + qhead

    hipLaunchKernelGGL(k_h0, dim3(1), dim3(HVD), 0, stream,
                       vb1, vW2, vb2, vW3, vb3, h0g);

    hipLaunchKernelGGL(k_setup, dim3(BN / GPB), dim3(256), 0, stream,
                       x, fW1, fb1, fW2, fb2, fW3, fb3,
                       vW1, vb1, vW2, vb2, vW3, vb3,
                       h0g, out, cnt, list, tgt);

    hipLaunchKernelGGL(k_solve, dim3(NQBLK), dim3(64), 0, stream,
                       vW1, vb1, vW2, vb2, vW3, vb3,
                       h0g, out, cnt, list, tgt, qhead);
}

// Round 8
// 500.119 us; speedup vs baseline: 1.3477x; 1.1524x over previous
//
#include <hip/hip_runtime.h>
#include <math.h>

#define BETA_C   0.99f
#define TOL_C    1e-4f
#define MAXIT_C  1000
#define EPS_C    1e-3f
#define BN       65536
#define NN       32
#define HFD      25
#define HVD      128
#define KVD      8
#define G        16   // lanes per cooperative group
#define GPB      16   // groups per 256-thread block (k_setup; 2 samples/group)
#define SGPB     4    // groups per 64-thread block (k_solve)
#define NQBLK    3072 // persistent solver blocks (queue-drained)

// wave-internal LDS ordering (groups live inside one wave; no block barrier
// inside the divergent solve loop).
__device__ __forceinline__ void wsync() {
    __builtin_amdgcn_wave_barrier();
    __threadfence_block();
    __builtin_amdgcn_wave_barrier();
}

__device__ __forceinline__ float sp_(float x) {
    return fmaxf(x, 0.f) + log1pf(expf(-fabsf(x)));
}
__device__ __forceinline__ void spsig_(float x, float& sp, float& sg) {
    float t = expf(-fabsf(x));
    sp = fmaxf(x, 0.f) + log1pf(t);
    float r = 1.f / (1.f + t);
    sg = (x >= 0.f) ? r : t * r;
}
__device__ __forceinline__ float sgn_(float d) {
    return (d > 0.f) ? 1.f : ((d < 0.f) ? -1.f : 0.f);
}

// ---------------------------------------------------------------------------
// layer1 for one input (k_solve): u_k = fx . W1[:,k], lane's 8 k's
__device__ __forceinline__ void layer1_u1(
    const int gl, const float* __restrict__ fx,
    const float* __restrict__ vW1, float (&u)[8])
{
    const int k0 = gl * 8;
#pragma unroll
    for (int j = 0; j < 8; ++j) u[j] = 0.f;
#pragma unroll
    for (int i = 0; i < NN; ++i) {
        const float4 wa = *(const float4*)(vW1 + i * HVD + k0);
        const float4 wb = *(const float4*)(vW1 + i * HVD + k0 + 4);
        const float xv = fx[i];
        u[0] = fmaf(xv, wa.x, u[0]); u[1] = fmaf(xv, wa.y, u[1]);
        u[2] = fmaf(xv, wa.z, u[2]); u[3] = fmaf(xv, wa.w, u[3]);
        u[4] = fmaf(xv, wb.x, u[4]); u[5] = fmaf(xv, wb.y, u[5]);
        u[6] = fmaf(xv, wb.z, u[6]); u[7] = fmaf(xv, wb.w, u[7]);
    }
}

// ---------------------------------------------------------------------------
// single TAN eval from cached u (k_solve): V(fx*g), dV/dg.
// Biases/offsets preloaded in regs; h1/dh1 packed as float4 pairs (2 k's).
__device__ __forceinline__ void veval1_tan(
    const int gl, const float (&u)[8], const float g,
    float4* h1q, const float n2,
    const float (&b1v)[8], const float (&b2v)[8], const float (&d0c)[8],
    const float* __restrict__ vW2, const float* __restrict__ vW3,
    float& Vout, float& dVout)
{
    const int k0 = gl * 8;
#pragma unroll
    for (int j = 0; j < 8; j += 2) {
        const float pre0 = fmaf(g, u[j],     b1v[j]);
        const float pre1 = fmaf(g, u[j + 1], b1v[j + 1]);
        float sp0, sg0, sp1, sg1;
        spsig_(pre0, sp0, sg0);
        spsig_(pre1, sp1, sg1);
        h1q[(k0 + j) >> 1] = make_float4(sp0, sg0 * u[j], sp1, sg1 * u[j + 1]);
    }
    wsync();
    float acc[8], dacc[8];
#pragma unroll
    for (int j = 0; j < 8; ++j) { acc[j] = 0.f; dacc[j] = 0.f; }
#pragma unroll 2
    for (int kk = 0; kk < HVD / 2; ++kk) {
        const float4 q = h1q[kk];                       // (h1,dh1) x 2 k's
        const float* w0 = vW2 + (2 * kk) * HVD + k0;
        const float4 wa0 = *(const float4*)(w0);
        const float4 wb0 = *(const float4*)(w0 + 4);
        const float4 wa1 = *(const float4*)(w0 + HVD);
        const float4 wb1 = *(const float4*)(w0 + HVD + 4);
        acc[0] = fmaf(q.x, wa0.x, acc[0]); acc[1] = fmaf(q.x, wa0.y, acc[1]);
        acc[2] = fmaf(q.x, wa0.z, acc[2]); acc[3] = fmaf(q.x, wa0.w, acc[3]);
        acc[4] = fmaf(q.x, wb0.x, acc[4]); acc[5] = fmaf(q.x, wb0.y, acc[5]);
        acc[6] = fmaf(q.x, wb0.z, acc[6]); acc[7] = fmaf(q.x, wb0.w, acc[7]);
        dacc[0] = fmaf(q.y, wa0.x, dacc[0]); dacc[1] = fmaf(q.y, wa0.y, dacc[1]);
        dacc[2] = fmaf(q.y, wa0.z, dacc[2]); dacc[3] = fmaf(q.y, wa0.w, dacc[3]);
        dacc[4] = fmaf(q.y, wb0.x, dacc[4]); dacc[5] = fmaf(q.y, wb0.y, dacc[5]);
        dacc[6] = fmaf(q.y, wb0.z, dacc[6]); dacc[7] = fmaf(q.y, wb0.w, dacc[7]);
        acc[0] = fmaf(q.z, wa1.x, acc[0]); acc[1] = fmaf(q.z, wa1.y, acc[1]);
        acc[2] = fmaf(q.z, wa1.z, acc[2]); acc[3] = fmaf(q.z, wa1.w, acc[3]);
        acc[4] = fmaf(q.z, wb1.x, acc[4]); acc[5] = fmaf(q.z, wb1.y, acc[5]);
        acc[6] = fmaf(q.z, wb1.z, acc[6]); acc[7] = fmaf(q.z, wb1.w, acc[7]);
        dacc[0] = fmaf(q.w, wa1.x, dacc[0]); dacc[1] = fmaf(q.w, wa1.y, dacc[1]);
        dacc[2] = fmaf(q.w, wa1.z, dacc[2]); dacc[3] = fmaf(q.w, wa1.w, dacc[3]);
        dacc[4] = fmaf(q.w, wb1.x, dacc[4]); dacc[5] = fmaf(q.w, wb1.y, dacc[5]);
        dacc[6] = fmaf(q.w, wb1.z, dacc[6]); dacc[7] = fmaf(q.w, wb1.w, dacc[7]);
    }
    wsync();
    float o[KVD], dO[KVD];
#pragma unroll
    for (int c = 0; c < KVD; ++c) { o[c] = 0.f; dO[c] = 0.f; }
#pragma unroll
    for (int j = 0; j < 8; ++j) {
        const float pre2 = acc[j] + b2v[j];
        float h2, sg; spsig_(pre2, h2, sg);
        const float dh2 = sg * dacc[j];
        const float4 w3a = *(const float4*)(vW3 + (k0 + j) * KVD);
        const float4 w3b = *(const float4*)(vW3 + (k0 + j) * KVD + 4);
        o[0] = fmaf(h2, w3a.x, o[0]); o[1] = fmaf(h2, w3a.y, o[1]);
        o[2] = fmaf(h2, w3a.z, o[2]); o[3] = fmaf(h2, w3a.w, o[3]);
        o[4] = fmaf(h2, w3b.x, o[4]); o[5] = fmaf(h2, w3b.y, o[5]);
        o[6] = fmaf(h2, w3b.z, o[6]); o[7] = fmaf(h2, w3b.w, o[7]);
        dO[0] = fmaf(dh2, w3a.x, dO[0]); dO[1] = fmaf(dh2, w3a.y, dO[1]);
        dO[2] = fmaf(dh2, w3a.z, dO[2]); dO[3] = fmaf(dh2, w3a.w, dO[3]);
        dO[4] = fmaf(dh2, w3b.x, dO[4]); dO[5] = fmaf(dh2, w3b.y, dO[5]);
        dO[6] = fmaf(dh2, w3b.z, dO[6]); dO[7] = fmaf(dh2, w3b.w, dO[7]);
    }
#pragma unroll
    for (int m = 1; m < G; m <<= 1) {
#pragma unroll
        for (int c = 0; c < KVD; ++c) {
            o[c] += __shfl_xor(o[c], m);
            dO[c] += __shfl_xor(dO[c], m);
        }
    }
    float vv = 0.f, dv = 0.f;
#pragma unroll
    for (int c = 0; c < KVD; ++c) {
        const float d = o[c] + d0c[c];
        vv = fmaf(d, d, vv);
        dv = fmaf(d, dO[c], dv);
    }
    Vout = vv + EPS_C * g * g * n2;
    dVout = 2.f * dv + 2.f * EPS_C * g * n2;
}

// ---- h0 = V-MLP(0) : weight-only, one tiny block --------------------------
__global__ __launch_bounds__(128) void k_h0(
    const float* __restrict__ vb1, const float* __restrict__ vW2,
    const float* __restrict__ vb2, const float* __restrict__ vW3,
    const float* __restrict__ vb3, float* __restrict__ h0g)
{
    __shared__ float h1s[HVD];
    __shared__ float h2s[HVD];
    int j = threadIdx.x;
    h1s[j] = sp_(vb1[j]);
    __syncthreads();
    float a = vb2[j];
    for (int k = 0; k < HVD; ++k) a = fmaf(h1s[k], vW2[k * HVD + j], a);
    h2s[j] = sp_(a);
    __syncthreads();
    if (j < KVD) {
        float acc = vb3[j];
        for (int k = 0; k < HVD; ++k) acc = fmaf(h2s[k], vW3[k * KVD + j], acc);
        h0g[j] = acc;
    }
}

// ---- setup: 2 samples/group, fhat x2, then ONE weight pass for 4 V-inputs --
// h1 for the 4 inputs {x0,f0,x1,f1} packed as float4 per hidden unit:
// layer-2 per k = 1 ds_read_b128 (broadcast) + 2 global b128 + 32 FMA.
// Group stride (HVD+2 float4 = 520 floats, %32 = 8) puts the 4 groups of a
// wave 8 banks apart -> conflict-free broadcasts.
__global__ __launch_bounds__(256, 3) void k_setup(
    const float* __restrict__ x_g,
    const float* __restrict__ fW1, const float* __restrict__ fb1,
    const float* __restrict__ fW2, const float* __restrict__ fb2,
    const float* __restrict__ fW3, const float* __restrict__ fb3,
    const float* __restrict__ vW1, const float* __restrict__ vb1,
    const float* __restrict__ vW2, const float* __restrict__ vb2,
    const float* __restrict__ vW3, const float* __restrict__ vb3,
    const float* __restrict__ h0g,
    float* __restrict__ out,
    int* __restrict__ cnt, int* __restrict__ list, float* __restrict__ tgt)
{
    __shared__ __align__(16) float4 h1p[GPB][HVD + 2];   // 33.3 KB
    __shared__ __align__(16) float4 fxp[GPB][NN + 2];    // 8.7 KB
    __shared__ float fh1[GPB][HFD + 1];
    __shared__ float fh2[GPB][HFD + 1];
    __shared__ int   wcnt[4];
    __shared__ int   bbase;

    const int gi = threadIdx.x >> 4;
    const int gl = threadIdx.x & (G - 1);
    const int k0 = gl * 8;
    const int sb = (blockIdx.x * GPB + gi) * 2;
    const int s0 = sb, s1 = sb + 1;
    float4* fxr = fxp[gi];
    float4* h1r = h1p[gi];

    // stage x for both samples into packed rows (.x = sample0, .z = sample1)
    const float xa0 = x_g[(size_t)s0 * NN + gl];
    const float xa1 = x_g[(size_t)s0 * NN + gl + 16];
    const float xb0 = x_g[(size_t)s1 * NN + gl];
    const float xb1 = x_g[(size_t)s1 * NN + gl + 16];
    fxr[gl].x      = xa0;  fxr[gl + 16].x = xa1;
    fxr[gl].z      = xb0;  fxr[gl + 16].z = xb1;
    wsync();

    // ---- fhat for both samples (lane-parallel over hidden units)
    float fA0, fA1, fB0, fB1;
#pragma unroll
    for (int si = 0; si < 2; ++si) {
        for (int uu = gl; uu < HFD; uu += G) {
            float a = fb1[uu];
#pragma unroll
            for (int i = 0; i < NN; ++i) {
                const float xv = si ? fxr[i].z : fxr[i].x;
                a = fmaf(xv, fW1[i * HFD + uu], a);
            }
            fh1[gi][uu] = sp_(a);
        }
        wsync();
        for (int uu = gl; uu < HFD; uu += G) {
            float a = fb2[uu];
#pragma unroll
            for (int i = 0; i < HFD; ++i)
                a = fmaf(fh1[gi][i], fW2[i * HFD + uu], a);
            fh2[gi][uu] = sp_(a);
        }
        wsync();
        float fo0 = fb3[gl], fo1 = fb3[gl + 16];
#pragma unroll
        for (int i = 0; i < HFD; ++i) {
            const float h = fh2[gi][i];
            fo0 = fmaf(h, fW3[i * NN + gl], fo0);
            fo1 = fmaf(h, fW3[i * NN + gl + 16], fo1);
        }
        const int ss = si ? s1 : s0;
        out[(size_t)ss * NN + gl]      = fo0;
        out[(size_t)ss * NN + gl + 16] = fo1;
        if (si == 0) {
            fA0 = fo0; fA1 = fo1;
            fxr[gl].y = fo0; fxr[gl + 16].y = fo1;
        } else {
            fB0 = fo0; fB1 = fo1;
            fxr[gl].w = fo0; fxr[gl + 16].w = fo1;
        }
        wsync();   // fh1/fh2 reuse + packed-row visibility
    }

    // ---- n2 for the 4 inputs via register butterfly (group-uniform result)
    float p0 = fmaf(xa0, xa0, xa1 * xa1);
    float p1 = fmaf(fA0, fA0, fA1 * fA1);
    float p2 = fmaf(xb0, xb0, xb1 * xb1);
    float p3 = fmaf(fB0, fB0, fB1 * fB1);
#pragma unroll
    for (int m = 1; m < G; m <<= 1) {
        p0 += __shfl_xor(p0, m); p1 += __shfl_xor(p1, m);
        p2 += __shfl_xor(p2, m); p3 += __shfl_xor(p3, m);
    }

    // ---- layer 1 for 4 inputs (shared W1 loads)
    float u0[8], u1[8], u2[8], u3[8];
#pragma unroll
    for (int j = 0; j < 8; ++j) { u0[j] = 0.f; u1[j] = 0.f; u2[j] = 0.f; u3[j] = 0.f; }
#pragma unroll
    for (int i = 0; i < NN; ++i) {
        const float4 q = fxr[i];                       // broadcast
        const float4 wa = *(const float4*)(vW1 + i * HVD + k0);
        const float4 wb = *(const float4*)(vW1 + i * HVD + k0 + 4);
        u0[0] = fmaf(q.x, wa.x, u0[0]); u0[1] = fmaf(q.x, wa.y, u0[1]);
        u0[2] = fmaf(q.x, wa.z, u0[2]); u0[3] = fmaf(q.x, wa.w, u0[3]);
        u0[4] = fmaf(q.x, wb.x, u0[4]); u0[5] = fmaf(q.x, wb.y, u0[5]);
        u0[6] = fmaf(q.x, wb.z, u0[6]); u0[7] = fmaf(q.x, wb.w, u0[7]);
        u1[0] = fmaf(q.y, wa.x, u1[0]); u1[1] = fmaf(q.y, wa.y, u1[1]);
        u1[2] = fmaf(q.y, wa.z, u1[2]); u1[3] = fmaf(q.y, wa.w, u1[3]);
        u1[4] = fmaf(q.y, wb.x, u1[4]); u1[5] = fmaf(q.y, wb.y, u1[5]);
        u1[6] = fmaf(q.y, wb.z, u1[6]); u1[7] = fmaf(q.y, wb.w, u1[7]);
        u2[0] = fmaf(q.z, wa.x, u2[0]); u2[1] = fmaf(q.z, wa.y, u2[1]);
        u2[2] = fmaf(q.z, wa.z, u2[2]); u2[3] = fmaf(q.z, wa.w, u2[3]);
        u2[4] = fmaf(q.z, wb.x, u2[4]); u2[5] = fmaf(q.z, wb.y, u2[5]);
        u2[6] = fmaf(q.z, wb.z, u2[6]); u2[7] = fmaf(q.z, wb.w, u2[7]);
        u3[0] = fmaf(q.w, wa.x, u3[0]); u3[1] = fmaf(q.w, wa.y, u3[1]);
        u3[2] = fmaf(q.w, wa.z, u3[2]); u3[3] = fmaf(q.w, wa.w, u3[3]);
        u3[4] = fmaf(q.w, wb.x, u3[4]); u3[5] = fmaf(q.w, wb.y, u3[5]);
        u3[6] = fmaf(q.w, wb.z, u3[6]); u3[7] = fmaf(q.w, wb.w, u3[7]);
    }
    {
        const float4 b1a = *(const float4*)(vb1 + k0);
        const float4 b1b = *(const float4*)(vb1 + k0 + 4);
        const float bv[8] = {b1a.x, b1a.y, b1a.z, b1a.w, b1b.x, b1b.y, b1b.z, b1b.w};
#pragma unroll
        for (int j = 0; j < 8; ++j) {
            h1r[k0 + j] = make_float4(sp_(u0[j] + bv[j]), sp_(u1[j] + bv[j]),
                                      sp_(u2[j] + bv[j]), sp_(u3[j] + bv[j]));
        }
    }
    wsync();

    // ---- layer 2 for 4 inputs: 1 b128 LDS + 2 b128 global per 32 FMA
    float a0[8], a1[8], a2[8], a3[8];
#pragma unroll
    for (int j = 0; j < 8; ++j) { a0[j] = 0.f; a1[j] = 0.f; a2[j] = 0.f; a3[j] = 0.f; }
#pragma unroll 4
    for (int k = 0; k < HVD; ++k) {
        const float4 q = h1r[k];                       // broadcast
        const float4 wa = *(const float4*)(vW2 + k * HVD + k0);
        const float4 wb = *(const float4*)(vW2 + k * HVD + k0 + 4);
        a0[0] = fmaf(q.x, wa.x, a0[0]); a0[1] = fmaf(q.x, wa.y, a0[1]);
        a0[2] = fmaf(q.x, wa.z, a0[2]); a0[3] = fmaf(q.x, wa.w, a0[3]);
        a0[4] = fmaf(q.x, wb.x, a0[4]); a0[5] = fmaf(q.x, wb.y, a0[5]);
        a0[6] = fmaf(q.x, wb.z, a0[6]); a0[7] = fmaf(q.x, wb.w, a0[7]);
        a1[0] = fmaf(q.y, wa.x, a1[0]); a1[1] = fmaf(q.y, wa.y, a1[1]);
        a1[2] = fmaf(q.y, wa.z, a1[2]); a1[3] = fmaf(q.y, wa.w, a1[3]);
        a1[4] = fmaf(q.y, wb.x, a1[4]); a1[5] = fmaf(q.y, wb.y, a1[5]);
        a1[6] = fmaf(q.y, wb.z, a1[6]); a1[7] = fmaf(q.y, wb.w, a1[7]);
        a2[0] = fmaf(q.z, wa.x, a2[0]); a2[1] = fmaf(q.z, wa.y, a2[1]);
        a2[2] = fmaf(q.z, wa.z, a2[2]); a2[3] = fmaf(q.z, wa.w, a2[3]);
        a2[4] = fmaf(q.z, wb.x, a2[4]); a2[5] = fmaf(q.z, wb.y, a2[5]);
        a2[6] = fmaf(q.z, wb.z, a2[6]); a2[7] = fmaf(q.z, wb.w, a2[7]);
        a3[0] = fmaf(q.w, wa.x, a3[0]); a3[1] = fmaf(q.w, wa.y, a3[1]);
        a3[2] = fmaf(q.w, wa.z, a3[2]); a3[3] = fmaf(q.w, wa.w, a3[3]);
        a3[4] = fmaf(q.w, wb.x, a3[4]); a3[5] = fmaf(q.w, wb.y, a3[5]);
        a3[6] = fmaf(q.w, wb.z, a3[6]); a3[7] = fmaf(q.w, wb.w, a3[7]);
    }

    // ---- layer 3 for 4 inputs (shared W3 loads)
    float o0[KVD], o1[KVD], o2[KVD], o3[KVD];
#pragma unroll
    for (int c = 0; c < KVD; ++c) { o0[c] = 0.f; o1[c] = 0.f; o2[c] = 0.f; o3[c] = 0.f; }
    {
        const float4 b2a = *(const float4*)(vb2 + k0);
        const float4 b2b = *(const float4*)(vb2 + k0 + 4);
        const float bv[8] = {b2a.x, b2a.y, b2a.z, b2a.w, b2b.x, b2b.y, b2b.z, b2b.w};
#pragma unroll
        for (int j = 0; j < 8; ++j) {
            const float h20 = sp_(a0[j] + bv[j]);
            const float h21 = sp_(a1[j] + bv[j]);
            const float h22 = sp_(a2[j] + bv[j]);
            const float h23 = sp_(a3[j] + bv[j]);
            const float4 w3a = *(const float4*)(vW3 + (k0 + j) * KVD);
            const float4 w3b = *(const float4*)(vW3 + (k0 + j) * KVD + 4);
            o0[0] = fmaf(h20, w3a.x, o0[0]); o0[1] = fmaf(h20, w3a.y, o0[1]);
            o0[2] = fmaf(h20, w3a.z, o0[2]); o0[3] = fmaf(h20, w3a.w, o0[3]);
            o0[4] = fmaf(h20, w3b.x, o0[4]); o0[5] = fmaf(h20, w3b.y, o0[5]);
            o0[6] = fmaf(h20, w3b.z, o0[6]); o0[7] = fmaf(h20, w3b.w, o0[7]);
            o1[0] = fmaf(h21, w3a.x, o1[0]); o1[1] = fmaf(h21, w3a.y, o1[1]);
            o1[2] = fmaf(h21, w3a.z, o1[2]); o1[3] = fmaf(h21, w3a.w, o1[3]);
            o1[4] = fmaf(h21, w3b.x, o1[4]); o1[5] = fmaf(h21, w3b.y, o1[5]);
            o1[6] = fmaf(h21, w3b.z, o1[6]); o1[7] = fmaf(h21, w3b.w, o1[7]);
            o2[0] = fmaf(h22, w3a.x, o2[0]); o2[1] = fmaf(h22, w3a.y, o2[1]);
            o2[2] = fmaf(h22, w3a.z, o2[2]); o2[3] = fmaf(h22, w3a.w, o2[3]);
            o2[4] = fmaf(h22, w3b.x, o2[4]); o2[5] = fmaf(h22, w3b.y, o2[5]);
            o2[6] = fmaf(h22, w3b.z, o2[6]); o2[7] = fmaf(h22, w3b.w, o2[7]);
            o3[0] = fmaf(h23, w3a.x, o3[0]); o3[1] = fmaf(h23, w3a.y, o3[1]);
            o3[2] = fmaf(h23, w3a.z, o3[2]); o3[3] = fmaf(h23, w3a.w, o3[3]);
            o3[4] = fmaf(h23, w3b.x, o3[4]); o3[5] = fmaf(h23, w3b.y, o3[5]);
            o3[6] = fmaf(h23, w3b.z, o3[6]); o3[7] = fmaf(h23, w3b.w, o3[7]);
        }
    }
#pragma unroll
    for (int m = 1; m < G; m <<= 1) {
#pragma unroll
        for (int c = 0; c < KVD; ++c) {
            o0[c] += __shfl_xor(o0[c], m);
            o1[c] += __shfl_xor(o1[c], m);
            o2[c] += __shfl_xor(o2[c], m);
            o3[c] += __shfl_xor(o3[c], m);
        }
    }
    float Vx0 = 0.f, Vf0 = 0.f, Vx1 = 0.f, Vf1 = 0.f;
#pragma unroll
    for (int c = 0; c < KVD; ++c) {
        const float d0 = (o0[c] + vb3[c]) - h0g[c];
        const float d1 = (o1[c] + vb3[c]) - h0g[c];
        const float d2 = (o2[c] + vb3[c]) - h0g[c];
        const float d3 = (o3[c] + vb3[c]) - h0g[c];
        Vx0 = fmaf(d0, d0, Vx0);
        Vf0 = fmaf(d1, d1, Vf0);
        Vx1 = fmaf(d2, d2, Vx1);
        Vf1 = fmaf(d3, d3, Vf1);
    }
    Vx0 += EPS_C * p0;  Vf0 += EPS_C * p1;     // g = 1
    Vx1 += EPS_C * p2;  Vf1 += EPS_C * p3;

    const float t0 = BETA_C * Vx0;
    const float t1 = BETA_C * Vx1;
    const bool act0 = (Vf0 - t0) > 0.f;        // group-uniform
    const bool act1 = (Vf1 - t1) > 0.f;

    // compaction: lane 0 carries sample0, lane 1 carries sample1
    const bool lead = (gl == 0 && act0) || (gl == 1 && act1);
    unsigned long long bal = __ballot(lead);
    const int lane = threadIdx.x & 63, wv = threadIdx.x >> 6;
    const int rank = __popcll(bal & ((1ull << lane) - 1ull));
    if (lane == 0) wcnt[wv] = __popcll(bal);
    __syncthreads();
    if (threadIdx.x == 0) {
        int tot = 0;
        for (int i = 0; i < 4; ++i) { int c = wcnt[i]; wcnt[i] = tot; tot += c; }
        bbase = atomicAdd(cnt, tot);
    }
    __syncthreads();
    if (lead) {
        const int p = bbase + wcnt[wv] + rank;
        list[p] = (gl == 0) ? s0 : s1;
        tgt[p]  = (gl == 0) ? t0 : t1;
    }
}

// ---- solver: persistent groups + global work queue (R6 verbatim) ----------
__global__ __launch_bounds__(64, 2) void k_solve(
    const float* __restrict__ vW1, const float* __restrict__ vb1,
    const float* __restrict__ vW2, const float* __restrict__ vb2,
    const float* __restrict__ vW3, const float* __restrict__ vb3,
    const float* __restrict__ h0g,
    float* __restrict__ out,
    const int* __restrict__ cnt, const int* __restrict__ list,
    const float* __restrict__ tgt, int* __restrict__ qhead)
{
    __shared__ __align__(16) float4 h1s[SGPB][HVD / 2 + 1];
    __shared__ float fxs[SGPB][NN + 2];

    const int gi = threadIdx.x >> 4;
    const int gl = threadIdx.x & (G - 1);
    const int n  = *cnt;
    float4* h1q  = h1s[gi];
    float*  fxrow = fxs[gi];
    const int lead = threadIdx.x & 48;      // wave lane of this group's lane 0

    int my;
    {
        int v = 0;
        if (gl == 0) v = atomicAdd(qhead, 1);
        my = __shfl(v, lead);
    }
    if (my >= n) return;                    // group-uniform

    // per-kernel invariants in registers
    const int k0 = gl * 8;
    float b1v[8], b2v[8], d0c[8];
    {
        const float4 a = *(const float4*)(vb1 + k0);
        const float4 b = *(const float4*)(vb1 + k0 + 4);
        b1v[0]=a.x; b1v[1]=a.y; b1v[2]=a.z; b1v[3]=a.w;
        b1v[4]=b.x; b1v[5]=b.y; b1v[6]=b.z; b1v[7]=b.w;
        const float4 c = *(const float4*)(vb2 + k0);
        const float4 d = *(const float4*)(vb2 + k0 + 4);
        b2v[0]=c.x; b2v[1]=c.y; b2v[2]=c.z; b2v[3]=c.w;
        b2v[4]=d.x; b2v[5]=d.y; b2v[6]=d.z; b2v[7]=d.w;
#pragma unroll
        for (int cix = 0; cix < KVD; ++cix) d0c[cix] = vb3[cix] - h0g[cix];
    }

    int s; float target, f0, f1, n2;
    float u[8];
    float gamma, e1, e2, v_e1, v_e2;
    bool pend; int it;

    auto init_sample = [&]() {
        s = list[my]; target = tgt[my];
        f0 = out[(size_t)s * NN + gl];
        f1 = out[(size_t)s * NN + gl + 16];
        fxrow[gl] = f0; fxrow[gl + 16] = f1;
        wsync();
        n2 = 0.f;
#pragma unroll
        for (int i = 0; i < NN; ++i) n2 = fmaf(fxrow[i], fxrow[i], n2);
        layer1_u1(gl, fxrow, vW1, u);
        gamma = 1.f; e1 = 0.f; e2 = 1.f;
        v_e1 = 0.f;      // V(fx*0) == 0 (target > 0, so sign(-target) < 0)
        v_e2 = 0.f;      // set at it==0
        pend = false; it = 0;
    };
    init_sample();

    for (;;) {
        float vp, dv;
        veval1_tan(gl, u, gamma, h1q, n2, b1v, b2v, d0c, vW2, vW3, vp, dv);
        if (pend) {
            const float sa = sgn_(vp - target);
            const float s1 = sgn_(v_e1 - target);
            const float s2 = sgn_(v_e2 - target);
            if (sa * s1 < 0.f) { e2 = gamma; v_e2 = vp; }
            if (sa * s2 < 0.f) { e1 = gamma; v_e1 = vp; }
            pend = false;
        }
        bool finish = false;
        if (it == 0) {
            v_e2 = vp;
        } else if (fabsf(vp - target) <= TOL_C) {
            finish = true;
        }
        if (!finish) {
            const float newt = gamma - (vp - target) / dv;
            if (newt >= e1 && newt <= e2) {   // NaN fails -> bisect
                gamma = newt;
            } else {
                gamma = 0.5f * (e1 + e2);
                pend = true;
            }
            ++it;
            if (it >= MAXIT_C) finish = true;
        }
        if (finish) {
            out[(size_t)s * NN + gl]      = f0 * gamma;
            out[(size_t)s * NN + gl + 16] = f1 * gamma;
            int v = 0;
            if (gl == 0) v = atomicAdd(qhead, 1);
            my = __shfl(v, lead);
            if (my >= n) break;               // group-uniform exit
            init_sample();
        }
    }
}

extern "C" void kernel_launch(void* const* d_in, const int* in_sizes, int n_in,
                              void* d_out, int out_size, void* d_ws, size_t ws_size,
                              hipStream_t stream)
{
    const float* x   = (const float*)d_in[0];
    const float* fW1 = (const float*)d_in[1];
    const float* fb1 = (const float*)d_in[2];
    const float* fW2 = (const float*)d_in[3];
    const float* fb2 = (const float*)d_in[4];
    const float* fW3 = (const float*)d_in[5];
    const float* fb3 = (const float*)d_in[6];
    const float* vW1 = (const float*)d_in[7];
    const float* vb1 = (const float*)d_in[8];
    const float* vW2 = (const float*)d_in[9];
    const float* vb2 = (const float*)d_in[10];
    const float* vW3 = (const float*)d_in[11];
    const float* vb3 = (const float*)d_in[12];
    float* out = (float*)d_out;

    char* ws = (char*)d_ws;
    int*   cnt   = (int*)ws;                                 // 4 B
    int*   qhead = (int*)(ws + 4);                           // 4 B
    float* h0g   = (float*)(ws + 64);                        // 8 floats
    int*   list  = (int*)(ws + 128);                         // BN ints
    float* tgt   = (float*)(ws + 128 + (size_t)BN * 4);      // BN floats

    hipMemsetAsync(ws, 0, 8, stream);                        // cnt + qhead

    hipLaunchKernelGGL(k_h0, dim3(1), dim3(HVD), 0, stream,
                       vb1, vW2, vb2, vW3, vb3, h0g);

    hipLaunchKernelGGL(k_setup, dim3(BN / (GPB * 2)), dim3(256), 0, stream,
                       x, fW1, fb1, fW2, fb2, fW3, fb3,
                       vW1, vb1, vW2, vb2, vW3, vb3,
                       h0g, out, cnt, list, tgt);

    hipLaunchKernelGGL(k_solve, dim3(NQBLK), dim3(64), 0, stream,
                       vW1, vb1, vW2, vb2, vW3, vb3,
                       h0g, out, cnt, list, tgt, qhead);
}

// Round 9
// 437.073 us; speedup vs baseline: 1.5421x; 1.1442x over previous
//
#include <hip/hip_runtime.h>
#include <math.h>

#define BETA_C   0.99f
#define TOL_C    1e-4f
#define MAXIT_C  1000
#define EPS_C    1e-3f
#define BN       65536
#define NN       32
#define HFD      25
#define HVD      128
#define KVD      8
#define G        16   // lanes per cooperative group
#define GPB      16   // groups per 256-thread block (k_setup; 2 samples/group)
#define SGPB     4    // groups per 64-thread block (k_solve)
#define NQBLK    3072 // persistent solver blocks (queue-drained)

// wave-internal LDS ordering (groups live inside one wave; no block barrier
// inside the divergent solve loop).
__device__ __forceinline__ void wsync() {
    __builtin_amdgcn_wave_barrier();
    __threadfence_block();
    __builtin_amdgcn_wave_barrier();
}

__device__ __forceinline__ float sp_(float x) {
    return fmaxf(x, 0.f) + log1pf(expf(-fabsf(x)));
}
__device__ __forceinline__ void spsig_(float x, float& sp, float& sg) {
    float t = expf(-fabsf(x));
    sp = fmaxf(x, 0.f) + log1pf(t);
    float r = 1.f / (1.f + t);
    sg = (x >= 0.f) ? r : t * r;
}
__device__ __forceinline__ float sgn_(float d) {
    return (d > 0.f) ? 1.f : ((d < 0.f) ? -1.f : 0.f);
}

// ---------------------------------------------------------------------------
// layer1 for one input (k_solve): u_k = fx . W1[:,k], lane's 8 k's
__device__ __forceinline__ void layer1_u1(
    const int gl, const float* __restrict__ fx,
    const float* __restrict__ vW1, float (&u)[8])
{
    const int k0 = gl * 8;
#pragma unroll
    for (int j = 0; j < 8; ++j) u[j] = 0.f;
#pragma unroll
    for (int i = 0; i < NN; ++i) {
        const float4 wa = *(const float4*)(vW1 + i * HVD + k0);
        const float4 wb = *(const float4*)(vW1 + i * HVD + k0 + 4);
        const float xv = fx[i];
        u[0] = fmaf(xv, wa.x, u[0]); u[1] = fmaf(xv, wa.y, u[1]);
        u[2] = fmaf(xv, wa.z, u[2]); u[3] = fmaf(xv, wa.w, u[3]);
        u[4] = fmaf(xv, wb.x, u[4]); u[5] = fmaf(xv, wb.y, u[5]);
        u[6] = fmaf(xv, wb.z, u[6]); u[7] = fmaf(xv, wb.w, u[7]);
    }
}

// ---------------------------------------------------------------------------
// single TAN eval from cached u (k_solve): V(fx*g), dV/dg.
// Biases/offsets preloaded in regs; h1/dh1 packed as float4 pairs (2 k's).
__device__ __forceinline__ void veval1_tan(
    const int gl, const float (&u)[8], const float g,
    float4* h1q, const float n2,
    const float (&b1v)[8], const float (&b2v)[8], const float (&d0c)[8],
    const float* __restrict__ vW2, const float* __restrict__ vW3,
    float& Vout, float& dVout)
{
    const int k0 = gl * 8;
#pragma unroll
    for (int j = 0; j < 8; j += 2) {
        const float pre0 = fmaf(g, u[j],     b1v[j]);
        const float pre1 = fmaf(g, u[j + 1], b1v[j + 1]);
        float sp0, sg0, sp1, sg1;
        spsig_(pre0, sp0, sg0);
        spsig_(pre1, sp1, sg1);
        h1q[(k0 + j) >> 1] = make_float4(sp0, sg0 * u[j], sp1, sg1 * u[j + 1]);
    }
    wsync();
    float acc[8], dacc[8];
#pragma unroll
    for (int j = 0; j < 8; ++j) { acc[j] = 0.f; dacc[j] = 0.f; }
#pragma unroll 2
    for (int kk = 0; kk < HVD / 2; ++kk) {
        const float4 q = h1q[kk];                       // (h1,dh1) x 2 k's
        const float* w0 = vW2 + (2 * kk) * HVD + k0;
        const float4 wa0 = *(const float4*)(w0);
        const float4 wb0 = *(const float4*)(w0 + 4);
        const float4 wa1 = *(const float4*)(w0 + HVD);
        const float4 wb1 = *(const float4*)(w0 + HVD + 4);
        acc[0] = fmaf(q.x, wa0.x, acc[0]); acc[1] = fmaf(q.x, wa0.y, acc[1]);
        acc[2] = fmaf(q.x, wa0.z, acc[2]); acc[3] = fmaf(q.x, wa0.w, acc[3]);
        acc[4] = fmaf(q.x, wb0.x, acc[4]); acc[5] = fmaf(q.x, wb0.y, acc[5]);
        acc[6] = fmaf(q.x, wb0.z, acc[6]); acc[7] = fmaf(q.x, wb0.w, acc[7]);
        dacc[0] = fmaf(q.y, wa0.x, dacc[0]); dacc[1] = fmaf(q.y, wa0.y, dacc[1]);
        dacc[2] = fmaf(q.y, wa0.z, dacc[2]); dacc[3] = fmaf(q.y, wa0.w, dacc[3]);
        dacc[4] = fmaf(q.y, wb0.x, dacc[4]); dacc[5] = fmaf(q.y, wb0.y, dacc[5]);
        dacc[6] = fmaf(q.y, wb0.z, dacc[6]); dacc[7] = fmaf(q.y, wb0.w, dacc[7]);
        acc[0] = fmaf(q.z, wa1.x, acc[0]); acc[1] = fmaf(q.z, wa1.y, acc[1]);
        acc[2] = fmaf(q.z, wa1.z, acc[2]); acc[3] = fmaf(q.z, wa1.w, acc[3]);
        acc[4] = fmaf(q.z, wb1.x, acc[4]); acc[5] = fmaf(q.z, wb1.y, acc[5]);
        acc[6] = fmaf(q.z, wb1.z, acc[6]); acc[7] = fmaf(q.z, wb1.w, acc[7]);
        dacc[0] = fmaf(q.w, wa1.x, dacc[0]); dacc[1] = fmaf(q.w, wa1.y, dacc[1]);
        dacc[2] = fmaf(q.w, wa1.z, dacc[2]); dacc[3] = fmaf(q.w, wa1.w, dacc[3]);
        dacc[4] = fmaf(q.w, wb1.x, dacc[4]); dacc[5] = fmaf(q.w, wb1.y, dacc[5]);
        dacc[6] = fmaf(q.w, wb1.z, dacc[6]); dacc[7] = fmaf(q.w, wb1.w, dacc[7]);
    }
    wsync();
    float o[KVD], dO[KVD];
#pragma unroll
    for (int c = 0; c < KVD; ++c) { o[c] = 0.f; dO[c] = 0.f; }
#pragma unroll
    for (int j = 0; j < 8; ++j) {
        const float pre2 = acc[j] + b2v[j];
        float h2, sg; spsig_(pre2, h2, sg);
        const float dh2 = sg * dacc[j];
        const float4 w3a = *(const float4*)(vW3 + (k0 + j) * KVD);
        const float4 w3b = *(const float4*)(vW3 + (k0 + j) * KVD + 4);
        o[0] = fmaf(h2, w3a.x, o[0]); o[1] = fmaf(h2, w3a.y, o[1]);
        o[2] = fmaf(h2, w3a.z, o[2]); o[3] = fmaf(h2, w3a.w, o[3]);
        o[4] = fmaf(h2, w3b.x, o[4]); o[5] = fmaf(h2, w3b.y, o[5]);
        o[6] = fmaf(h2, w3b.z, o[6]); o[7] = fmaf(h2, w3b.w, o[7]);
        dO[0] = fmaf(dh2, w3a.x, dO[0]); dO[1] = fmaf(dh2, w3a.y, dO[1]);
        dO[2] = fmaf(dh2, w3a.z, dO[2]); dO[3] = fmaf(dh2, w3a.w, dO[3]);
        dO[4] = fmaf(dh2, w3b.x, dO[4]); dO[5] = fmaf(dh2, w3b.y, dO[5]);
        dO[6] = fmaf(dh2, w3b.z, dO[6]); dO[7] = fmaf(dh2, w3b.w, dO[7]);
    }
#pragma unroll
    for (int m = 1; m < G; m <<= 1) {
#pragma unroll
        for (int c = 0; c < KVD; ++c) {
            o[c] += __shfl_xor(o[c], m);
            dO[c] += __shfl_xor(dO[c], m);
        }
    }
    float vv = 0.f, dv = 0.f;
#pragma unroll
    for (int c = 0; c < KVD; ++c) {
        const float d = o[c] + d0c[c];
        vv = fmaf(d, d, vv);
        dv = fmaf(d, dO[c], dv);
    }
    Vout = vv + EPS_C * g * g * n2;
    dVout = 2.f * dv + 2.f * EPS_C * g * n2;
}

// ---- h0 = V-MLP(0) : weight-only, one tiny block --------------------------
__global__ __launch_bounds__(128) void k_h0(
    const float* __restrict__ vb1, const float* __restrict__ vW2,
    const float* __restrict__ vb2, const float* __restrict__ vW3,
    const float* __restrict__ vb3, float* __restrict__ h0g)
{
    __shared__ float h1s[HVD];
    __shared__ float h2s[HVD];
    int j = threadIdx.x;
    h1s[j] = sp_(vb1[j]);
    __syncthreads();
    float a = vb2[j];
    for (int k = 0; k < HVD; ++k) a = fmaf(h1s[k], vW2[k * HVD + j], a);
    h2s[j] = sp_(a);
    __syncthreads();
    if (j < KVD) {
        float acc = vb3[j];
        for (int k = 0; k < HVD; ++k) acc = fmaf(h2s[k], vW3[k * KVD + j], acc);
        h0g[j] = acc;
    }
}

// ---- setup: 2 samples/group, fhat x2, then ONE weight pass for 4 V-inputs --
// Also stores Vf per active sample so the solver can seed gamma0 = sqrt(t/Vf)
// and skip the gamma=1 eval entirely (V(1)=Vf known).
__global__ __launch_bounds__(256, 3) void k_setup(
    const float* __restrict__ x_g,
    const float* __restrict__ fW1, const float* __restrict__ fb1,
    const float* __restrict__ fW2, const float* __restrict__ fb2,
    const float* __restrict__ fW3, const float* __restrict__ fb3,
    const float* __restrict__ vW1, const float* __restrict__ vb1,
    const float* __restrict__ vW2, const float* __restrict__ vb2,
    const float* __restrict__ vW3, const float* __restrict__ vb3,
    const float* __restrict__ h0g,
    float* __restrict__ out,
    int* __restrict__ cnt, int* __restrict__ list, float* __restrict__ tgt,
    float* __restrict__ vfb)
{
    __shared__ __align__(16) float4 h1p[GPB][HVD + 2];   // 33.3 KB
    __shared__ __align__(16) float4 fxp[GPB][NN + 2];    // 8.7 KB
    __shared__ float fh1[GPB][HFD + 1];
    __shared__ float fh2[GPB][HFD + 1];
    __shared__ int   wcnt[4];
    __shared__ int   bbase;

    const int gi = threadIdx.x >> 4;
    const int gl = threadIdx.x & (G - 1);
    const int k0 = gl * 8;
    const int sb = (blockIdx.x * GPB + gi) * 2;
    const int s0 = sb, s1 = sb + 1;
    float4* fxr = fxp[gi];
    float4* h1r = h1p[gi];

    // stage x for both samples into packed rows (.x = sample0, .z = sample1)
    const float xa0 = x_g[(size_t)s0 * NN + gl];
    const float xa1 = x_g[(size_t)s0 * NN + gl + 16];
    const float xb0 = x_g[(size_t)s1 * NN + gl];
    const float xb1 = x_g[(size_t)s1 * NN + gl + 16];
    fxr[gl].x      = xa0;  fxr[gl + 16].x = xa1;
    fxr[gl].z      = xb0;  fxr[gl + 16].z = xb1;
    wsync();

    // ---- fhat for both samples (lane-parallel over hidden units)
    float fA0, fA1, fB0, fB1;
#pragma unroll
    for (int si = 0; si < 2; ++si) {
        for (int uu = gl; uu < HFD; uu += G) {
            float a = fb1[uu];
#pragma unroll
            for (int i = 0; i < NN; ++i) {
                const float xv = si ? fxr[i].z : fxr[i].x;
                a = fmaf(xv, fW1[i * HFD + uu], a);
            }
            fh1[gi][uu] = sp_(a);
        }
        wsync();
        for (int uu = gl; uu < HFD; uu += G) {
            float a = fb2[uu];
#pragma unroll
            for (int i = 0; i < HFD; ++i)
                a = fmaf(fh1[gi][i], fW2[i * HFD + uu], a);
            fh2[gi][uu] = sp_(a);
        }
        wsync();
        float fo0 = fb3[gl], fo1 = fb3[gl + 16];
#pragma unroll
        for (int i = 0; i < HFD; ++i) {
            const float h = fh2[gi][i];
            fo0 = fmaf(h, fW3[i * NN + gl], fo0);
            fo1 = fmaf(h, fW3[i * NN + gl + 16], fo1);
        }
        const int ss = si ? s1 : s0;
        out[(size_t)ss * NN + gl]      = fo0;
        out[(size_t)ss * NN + gl + 16] = fo1;
        if (si == 0) {
            fA0 = fo0; fA1 = fo1;
            fxr[gl].y = fo0; fxr[gl + 16].y = fo1;
        } else {
            fB0 = fo0; fB1 = fo1;
            fxr[gl].w = fo0; fxr[gl + 16].w = fo1;
        }
        wsync();   // fh1/fh2 reuse + packed-row visibility
    }

    // ---- n2 for the 4 inputs via register butterfly (group-uniform result)
    float p0 = fmaf(xa0, xa0, xa1 * xa1);
    float p1 = fmaf(fA0, fA0, fA1 * fA1);
    float p2 = fmaf(xb0, xb0, xb1 * xb1);
    float p3 = fmaf(fB0, fB0, fB1 * fB1);
#pragma unroll
    for (int m = 1; m < G; m <<= 1) {
        p0 += __shfl_xor(p0, m); p1 += __shfl_xor(p1, m);
        p2 += __shfl_xor(p2, m); p3 += __shfl_xor(p3, m);
    }

    // ---- layer 1 for 4 inputs (shared W1 loads)
    float u0[8], u1[8], u2[8], u3[8];
#pragma unroll
    for (int j = 0; j < 8; ++j) { u0[j] = 0.f; u1[j] = 0.f; u2[j] = 0.f; u3[j] = 0.f; }
#pragma unroll
    for (int i = 0; i < NN; ++i) {
        const float4 q = fxr[i];                       // broadcast
        const float4 wa = *(const float4*)(vW1 + i * HVD + k0);
        const float4 wb = *(const float4*)(vW1 + i * HVD + k0 + 4);
        u0[0] = fmaf(q.x, wa.x, u0[0]); u0[1] = fmaf(q.x, wa.y, u0[1]);
        u0[2] = fmaf(q.x, wa.z, u0[2]); u0[3] = fmaf(q.x, wa.w, u0[3]);
        u0[4] = fmaf(q.x, wb.x, u0[4]); u0[5] = fmaf(q.x, wb.y, u0[5]);
        u0[6] = fmaf(q.x, wb.z, u0[6]); u0[7] = fmaf(q.x, wb.w, u0[7]);
        u1[0] = fmaf(q.y, wa.x, u1[0]); u1[1] = fmaf(q.y, wa.y, u1[1]);
        u1[2] = fmaf(q.y, wa.z, u1[2]); u1[3] = fmaf(q.y, wa.w, u1[3]);
        u1[4] = fmaf(q.y, wb.x, u1[4]); u1[5] = fmaf(q.y, wb.y, u1[5]);
        u1[6] = fmaf(q.y, wb.z, u1[6]); u1[7] = fmaf(q.y, wb.w, u1[7]);
        u2[0] = fmaf(q.z, wa.x, u2[0]); u2[1] = fmaf(q.z, wa.y, u2[1]);
        u2[2] = fmaf(q.z, wa.z, u2[2]); u2[3] = fmaf(q.z, wa.w, u2[3]);
        u2[4] = fmaf(q.z, wb.x, u2[4]); u2[5] = fmaf(q.z, wb.y, u2[5]);
        u2[6] = fmaf(q.z, wb.z, u2[6]); u2[7] = fmaf(q.z, wb.w, u2[7]);
        u3[0] = fmaf(q.w, wa.x, u3[0]); u3[1] = fmaf(q.w, wa.y, u3[1]);
        u3[2] = fmaf(q.w, wa.z, u3[2]); u3[3] = fmaf(q.w, wa.w, u3[3]);
        u3[4] = fmaf(q.w, wb.x, u3[4]); u3[5] = fmaf(q.w, wb.y, u3[5]);
        u3[6] = fmaf(q.w, wb.z, u3[6]); u3[7] = fmaf(q.w, wb.w, u3[7]);
    }
    {
        const float4 b1a = *(const float4*)(vb1 + k0);
        const float4 b1b = *(const float4*)(vb1 + k0 + 4);
        const float bv[8] = {b1a.x, b1a.y, b1a.z, b1a.w, b1b.x, b1b.y, b1b.z, b1b.w};
#pragma unroll
        for (int j = 0; j < 8; ++j) {
            h1r[k0 + j] = make_float4(sp_(u0[j] + bv[j]), sp_(u1[j] + bv[j]),
                                      sp_(u2[j] + bv[j]), sp_(u3[j] + bv[j]));
        }
    }
    wsync();

    // ---- layer 2 for 4 inputs: 1 b128 LDS + 2 b128 global per 32 FMA
    float a0[8], a1[8], a2[8], a3[8];
#pragma unroll
    for (int j = 0; j < 8; ++j) { a0[j] = 0.f; a1[j] = 0.f; a2[j] = 0.f; a3[j] = 0.f; }
#pragma unroll 4
    for (int k = 0; k < HVD; ++k) {
        const float4 q = h1r[k];                       // broadcast
        const float4 wa = *(const float4*)(vW2 + k * HVD + k0);
        const float4 wb = *(const float4*)(vW2 + k * HVD + k0 + 4);
        a0[0] = fmaf(q.x, wa.x, a0[0]); a0[1] = fmaf(q.x, wa.y, a0[1]);
        a0[2] = fmaf(q.x, wa.z, a0[2]); a0[3] = fmaf(q.x, wa.w, a0[3]);
        a0[4] = fmaf(q.x, wb.x, a0[4]); a0[5] = fmaf(q.x, wb.y, a0[5]);
        a0[6] = fmaf(q.x, wb.z, a0[6]); a0[7] = fmaf(q.x, wb.w, a0[7]);
        a1[0] = fmaf(q.y, wa.x, a1[0]); a1[1] = fmaf(q.y, wa.y, a1[1]);
        a1[2] = fmaf(q.y, wa.z, a1[2]); a1[3] = fmaf(q.y, wa.w, a1[3]);
        a1[4] = fmaf(q.y, wb.x, a1[4]); a1[5] = fmaf(q.y, wb.y, a1[5]);
        a1[6] = fmaf(q.y, wb.z, a1[6]); a1[7] = fmaf(q.y, wb.w, a1[7]);
        a2[0] = fmaf(q.z, wa.x, a2[0]); a2[1] = fmaf(q.z, wa.y, a2[1]);
        a2[2] = fmaf(q.z, wa.z, a2[2]); a2[3] = fmaf(q.z, wa.w, a2[3]);
        a2[4] = fmaf(q.z, wb.x, a2[4]); a2[5] = fmaf(q.z, wb.y, a2[5]);
        a2[6] = fmaf(q.z, wb.z, a2[6]); a2[7] = fmaf(q.z, wb.w, a2[7]);
        a3[0] = fmaf(q.w, wa.x, a3[0]); a3[1] = fmaf(q.w, wa.y, a3[1]);
        a3[2] = fmaf(q.w, wa.z, a3[2]); a3[3] = fmaf(q.w, wa.w, a3[3]);
        a3[4] = fmaf(q.w, wb.x, a3[4]); a3[5] = fmaf(q.w, wb.y, a3[5]);
        a3[6] = fmaf(q.w, wb.z, a3[6]); a3[7] = fmaf(q.w, wb.w, a3[7]);
    }

    // ---- layer 3 for 4 inputs (shared W3 loads)
    float o0[KVD], o1[KVD], o2[KVD], o3[KVD];
#pragma unroll
    for (int c = 0; c < KVD; ++c) { o0[c] = 0.f; o1[c] = 0.f; o2[c] = 0.f; o3[c] = 0.f; }
    {
        const float4 b2a = *(const float4*)(vb2 + k0);
        const float4 b2b = *(const float4*)(vb2 + k0 + 4);
        const float bv[8] = {b2a.x, b2a.y, b2a.z, b2a.w, b2b.x, b2b.y, b2b.z, b2b.w};
#pragma unroll
        for (int j = 0; j < 8; ++j) {
            const float h20 = sp_(a0[j] + bv[j]);
            const float h21 = sp_(a1[j] + bv[j]);
            const float h22 = sp_(a2[j] + bv[j]);
            const float h23 = sp_(a3[j] + bv[j]);
            const float4 w3a = *(const float4*)(vW3 + (k0 + j) * KVD);
            const float4 w3b = *(const float4*)(vW3 + (k0 + j) * KVD + 4);
            o0[0] = fmaf(h20, w3a.x, o0[0]); o0[1] = fmaf(h20, w3a.y, o0[1]);
            o0[2] = fmaf(h20, w3a.z, o0[2]); o0[3] = fmaf(h20, w3a.w, o0[3]);
            o0[4] = fmaf(h20, w3b.x, o0[4]); o0[5] = fmaf(h20, w3b.y, o0[5]);
            o0[6] = fmaf(h20, w3b.z, o0[6]); o0[7] = fmaf(h20, w3b.w, o0[7]);
            o1[0] = fmaf(h21, w3a.x, o1[0]); o1[1] = fmaf(h21, w3a.y, o1[1]);
            o1[2] = fmaf(h21, w3a.z, o1[2]); o1[3] = fmaf(h21, w3a.w, o1[3]);
            o1[4] = fmaf(h21, w3b.x, o1[4]); o1[5] = fmaf(h21, w3b.y, o1[5]);
            o1[6] = fmaf(h21, w3b.z, o1[6]); o1[7] = fmaf(h21, w3b.w, o1[7]);
            o2[0] = fmaf(h22, w3a.x, o2[0]); o2[1] = fmaf(h22, w3a.y, o2[1]);
            o2[2] = fmaf(h22, w3a.z, o2[2]); o2[3] = fmaf(h22, w3a.w, o2[3]);
            o2[4] = fmaf(h22, w3b.x, o2[4]); o2[5] = fmaf(h22, w3b.y, o2[5]);
            o2[6] = fmaf(h22, w3b.z, o2[6]); o2[7] = fmaf(h22, w3b.w, o2[7]);
            o3[0] = fmaf(h23, w3a.x, o3[0]); o3[1] = fmaf(h23, w3a.y, o3[1]);
            o3[2] = fmaf(h23, w3a.z, o3[2]); o3[3] = fmaf(h23, w3a.w, o3[3]);
            o3[4] = fmaf(h23, w3b.x, o3[4]); o3[5] = fmaf(h23, w3b.y, o3[5]);
            o3[6] = fmaf(h23, w3b.z, o3[6]); o3[7] = fmaf(h23, w3b.w, o3[7]);
        }
    }
#pragma unroll
    for (int m = 1; m < G; m <<= 1) {
#pragma unroll
        for (int c = 0; c < KVD; ++c) {
            o0[c] += __shfl_xor(o0[c], m);
            o1[c] += __shfl_xor(o1[c], m);
            o2[c] += __shfl_xor(o2[c], m);
            o3[c] += __shfl_xor(o3[c], m);
        }
    }
    float Vx0 = 0.f, Vf0 = 0.f, Vx1 = 0.f, Vf1 = 0.f;
#pragma unroll
    for (int c = 0; c < KVD; ++c) {
        const float d0 = (o0[c] + vb3[c]) - h0g[c];
        const float d1 = (o1[c] + vb3[c]) - h0g[c];
        const float d2 = (o2[c] + vb3[c]) - h0g[c];
        const float d3 = (o3[c] + vb3[c]) - h0g[c];
        Vx0 = fmaf(d0, d0, Vx0);
        Vf0 = fmaf(d1, d1, Vf0);
        Vx1 = fmaf(d2, d2, Vx1);
        Vf1 = fmaf(d3, d3, Vf1);
    }
    Vx0 += EPS_C * p0;  Vf0 += EPS_C * p1;     // g = 1
    Vx1 += EPS_C * p2;  Vf1 += EPS_C * p3;

    const float t0 = BETA_C * Vx0;
    const float t1 = BETA_C * Vx1;
    const bool act0 = (Vf0 - t0) > 0.f;        // group-uniform
    const bool act1 = (Vf1 - t1) > 0.f;

    // compaction: lane 0 carries sample0, lane 1 carries sample1
    const bool lead = (gl == 0 && act0) || (gl == 1 && act1);
    unsigned long long bal = __ballot(lead);
    const int lane = threadIdx.x & 63, wv = threadIdx.x >> 6;
    const int rank = __popcll(bal & ((1ull << lane) - 1ull));
    if (lane == 0) wcnt[wv] = __popcll(bal);
    __syncthreads();
    if (threadIdx.x == 0) {
        int tot = 0;
        for (int i = 0; i < 4; ++i) { int c = wcnt[i]; wcnt[i] = tot; tot += c; }
        bbase = atomicAdd(cnt, tot);
    }
    __syncthreads();
    if (lead) {
        const int p = bbase + wcnt[wv] + rank;
        list[p] = (gl == 0) ? s0 : s1;
        tgt[p]  = (gl == 0) ? t0 : t1;
        vfb[p]  = (gl == 0) ? Vf0 : Vf1;       // V(fhatx) — solver's V(1)
    }
}

// ---- solver: persistent groups + global work queue + sqrt-seeded Newton ---
// gamma0 = sqrt(target/Vf): exact root for quadratic V (V(0)=0), so Newton
// needs ~2-3 evals instead of ~6-7 from gamma=1. V(1)=Vf known -> no it==0
// eval. Brackets [0,1] with V values (0, Vf) valid from the start.
__global__ __launch_bounds__(64, 2) void k_solve(
    const float* __restrict__ vW1, const float* __restrict__ vb1,
    const float* __restrict__ vW2, const float* __restrict__ vb2,
    const float* __restrict__ vW3, const float* __restrict__ vb3,
    const float* __restrict__ h0g,
    float* __restrict__ out,
    const int* __restrict__ cnt, const int* __restrict__ list,
    const float* __restrict__ tgt, const float* __restrict__ vfb,
    int* __restrict__ qhead)
{
    __shared__ __align__(16) float4 h1s[SGPB][HVD / 2 + 1];
    __shared__ float fxs[SGPB][NN + 2];

    const int gi = threadIdx.x >> 4;
    const int gl = threadIdx.x & (G - 1);
    const int n  = *cnt;
    float4* h1q  = h1s[gi];
    float*  fxrow = fxs[gi];
    const int lead = threadIdx.x & 48;      // wave lane of this group's lane 0

    int my;
    {
        int v = 0;
        if (gl == 0) v = atomicAdd(qhead, 1);
        my = __shfl(v, lead);
    }
    if (my >= n) return;                    // group-uniform

    // per-kernel invariants in registers
    const int k0 = gl * 8;
    float b1v[8], b2v[8], d0c[8];
    {
        const float4 a = *(const float4*)(vb1 + k0);
        const float4 b = *(const float4*)(vb1 + k0 + 4);
        b1v[0]=a.x; b1v[1]=a.y; b1v[2]=a.z; b1v[3]=a.w;
        b1v[4]=b.x; b1v[5]=b.y; b1v[6]=b.z; b1v[7]=b.w;
        const float4 c = *(const float4*)(vb2 + k0);
        const float4 d = *(const float4*)(vb2 + k0 + 4);
        b2v[0]=c.x; b2v[1]=c.y; b2v[2]=c.z; b2v[3]=c.w;
        b2v[4]=d.x; b2v[5]=d.y; b2v[6]=d.z; b2v[7]=d.w;
#pragma unroll
        for (int cix = 0; cix < KVD; ++cix) d0c[cix] = vb3[cix] - h0g[cix];
    }

    int s; float target, f0, f1, n2;
    float u[8];
    float gamma, e1, e2, v_e1, v_e2;
    bool pend; int it;

    auto init_sample = [&]() {
        s = list[my]; target = tgt[my];
        const float vf = vfb[my];
        f0 = out[(size_t)s * NN + gl];
        f1 = out[(size_t)s * NN + gl + 16];
        fxrow[gl] = f0; fxrow[gl + 16] = f1;
        wsync();
        n2 = 0.f;
#pragma unroll
        for (int i = 0; i < NN; ++i) n2 = fmaf(fxrow[i], fxrow[i], n2);
        layer1_u1(gl, fxrow, vW1, u);
        e1 = 0.f; e2 = 1.f;
        v_e1 = 0.f;                   // V(fx*0) == 0
        v_e2 = vf;                    // V(fx*1) from k_setup
        gamma = sqrtf(target / vf);   // exact for quadratic V; in (0,1)
        pend = false; it = 0;
    };
    init_sample();

    for (;;) {
        float vp, dv;
        veval1_tan(gl, u, gamma, h1q, n2, b1v, b2v, d0c, vW2, vW3, vp, dv);
        if (pend) {
            const float sa = sgn_(vp - target);
            const float s1 = sgn_(v_e1 - target);
            const float s2 = sgn_(v_e2 - target);
            if (sa * s1 < 0.f) { e2 = gamma; v_e2 = vp; }
            if (sa * s2 < 0.f) { e1 = gamma; v_e1 = vp; }
            pend = false;
        }
        bool finish = false;
        if (fabsf(vp - target) <= TOL_C) {
            finish = true;
        } else {
            const float newt = gamma - (vp - target) / dv;
            if (newt >= e1 && newt <= e2) {   // NaN fails -> bisect
                gamma = newt;
            } else {
                gamma = 0.5f * (e1 + e2);
                pend = true;
            }
            ++it;
            if (it >= MAXIT_C) finish = true;
        }
        if (finish) {
            out[(size_t)s * NN + gl]      = f0 * gamma;
            out[(size_t)s * NN + gl + 16] = f1 * gamma;
            int v = 0;
            if (gl == 0) v = atomicAdd(qhead, 1);
            my = __shfl(v, lead);
            if (my >= n) break;               // group-uniform exit
            init_sample();
        }
    }
}

extern "C" void kernel_launch(void* const* d_in, const int* in_sizes, int n_in,
                              void* d_out, int out_size, void* d_ws, size_t ws_size,
                              hipStream_t stream)
{
    const float* x   = (const float*)d_in[0];
    const float* fW1 = (const float*)d_in[1];
    const float* fb1 = (const float*)d_in[2];
    const float* fW2 = (const float*)d_in[3];
    const float* fb2 = (const float*)d_in[4];
    const float* fW3 = (const float*)d_in[5];
    const float* fb3 = (const float*)d_in[6];
    const float* vW1 = (const float*)d_in[7];
    const float* vb1 = (const float*)d_in[8];
    const float* vW2 = (const float*)d_in[9];
    const float* vb2 = (const float*)d_in[10];
    const float* vW3 = (const float*)d_in[11];
    const float* vb3 = (const float*)d_in[12];
    float* out = (float*)d_out;

    char* ws = (char*)d_ws;
    int*   cnt   = (int*)ws;                                 // 4 B
    int*   qhead = (int*)(ws + 4);                           // 4 B
    float* h0g   = (float*)(ws + 64);                        // 8 floats
    int*   list  = (int*)(ws + 128);                         // BN ints
    float* tgt   = (float*)(ws + 128 + (size_t)BN * 4);      // BN floats
    float* vfb   = (float*)(ws + 128 + (size_t)BN * 8);      // BN floats

    hipMemsetAsync(ws, 0, 8, stream);                        // cnt + qhead

    hipLaunchKernelGGL(k_h0, dim3(1), dim3(HVD), 0, stream,
                       vb1, vW2, vb2, vW3, vb3, h0g);

    hipLaunchKernelGGL(k_setup, dim3(BN / (GPB * 2)), dim3(256), 0, stream,
                       x, fW1, fb1, fW2, fb2, fW3, fb3,
                       vW1, vb1, vW2, vb2, vW3, vb3,
                       h0g, out, cnt, list, tgt, vfb);

    hipLaunchKernelGGL(k_solve, dim3(NQBLK), dim3(64), 0, stream,
                       vW1, vb1, vW2, vb2, vW3, vb3,
                       h0g, out, cnt, list, tgt, vfb, qhead);
}